// Round 3
// baseline (1953.464 us; speedup 1.0000x reference)
//
#include <hip/hip_runtime.h>

#define H 224
#define W 224
#define HW (H*W)
#define BATCH 2
#define CIN 64
#define COUT 64
#define NOFF 18     // 2*9 offset channels
#define CCHUNK 16   // channels staged in LDS per chunk

// ---------------------------------------------------------------------------
// Offset conv: 3x3, pad 1. x (B,64,H,W) * w (18,64,3,3) + bias -> off (B,18,H,W)
// Block = 128 pixels x 2 groups of 9 output channels.
// ---------------------------------------------------------------------------
__global__ __launch_bounds__(256) void k_offconv(const float* __restrict__ x,
                                                 const float* __restrict__ w,
                                                 const float* __restrict__ bias,
                                                 float* __restrict__ off) {
    int tid = threadIdx.x;
    int pix = blockIdx.x * 128 + (tid & 127);   // grid = B*HW/128 blocks
    int grp = tid >> 7;                          // 0..1 -> 9 outputs each
    int b  = pix / HW;
    int ij = pix % HW;
    int i  = ij / W;
    int j  = ij % W;

    float acc[9];
#pragma unroll
    for (int o = 0; o < 9; ++o) acc[o] = bias[grp * 9 + o];

    const float* xb = x + b * CIN * HW;
    const float* wg = w + (grp * 9) * CIN * 9;
    for (int c = 0; c < CIN; ++c) {
        const float* xc = xb + c * HW;
        float v[9];
#pragma unroll
        for (int u = 0; u < 3; ++u) {
#pragma unroll
            for (int t = 0; t < 3; ++t) {
                int ii = i + u - 1, jj = j + t - 1;
                bool ok = (ii >= 0) & (ii < H) & (jj >= 0) & (jj < W);
                v[u * 3 + t] = ok ? xc[ii * W + jj] : 0.0f;
            }
        }
#pragma unroll
        for (int o = 0; o < 9; ++o) {
            float a = acc[o];
#pragma unroll
            for (int k = 0; k < 9; ++k)
                a += wg[(o * CIN + c) * 9 + k] * v[k];
            acc[o] = a;
        }
    }
#pragma unroll
    for (int o = 0; o < 9; ++o)
        off[(b * NOFF + grp * 9 + o) * HW + ij] = acc[o];
}

// ---------------------------------------------------------------------------
// Deformable sampling + (ks,stride-ks) conv collapsed to K=576 GEMM.
// Block = 256 threads = 64 pixels x 4 output-groups (16 outs each).
// Channels processed in 4 chunks of 16; per chunk:
//   Phase A: cooperative gather+bilinear -> LDS xo[16][64][9] (each gather
//            done once, shared by all 4 output groups).
//   Phase B: each thread (pix, grp) accumulates 16 outs from LDS fragments
//            with wave-uniform (scalar) weights.
// LDS stride per pixel = 9 floats (odd) -> only 2-way bank aliasing (free).
// ---------------------------------------------------------------------------
__global__ __launch_bounds__(256) void k_deform(const float* __restrict__ x,
                                                const float* __restrict__ off,
                                                const float* __restrict__ w,
                                                float* __restrict__ out) {
    __shared__ float xo_s[CCHUNK][64][9];       // 36 KB

    int tid  = threadIdx.x;
    int lpix = tid & 63;                         // pixel slot in block
    int row4 = tid >> 6;                         // 0..3: gather row / out-group
    int pix  = blockIdx.x * 64 + lpix;           // grid = B*HW/64 blocks
    int b  = pix / HW;
    int ij = pix % HW;
    int i  = ij / W;
    int j  = ij % W;

    // Bilinear setup (same for all 4 waves of this pixel; recomputed cheaply).
    const float* offb = off + b * NOFF * HW + ij;
    float g0[9], g1[9], g2[9], g3[9];
    int   i0[9], i1[9], i2[9], i3[9];
#pragma unroll
    for (int n = 0; n < 9; ++n) {
        int k1 = n / 3, k2 = n % 3;
        float px_f = (float)(i + k1) + offb[n * HW];
        float py_f = (float)(j + k2) + offb[(9 + n) * HW];
        float qx = floorf(px_f), qy = floorf(py_f);
        int ltx = min(max((int)qx, 0), H - 1);
        int lty = min(max((int)qy, 0), W - 1);
        int rbx = min(max((int)qx + 1, 0), H - 1);
        int rby = min(max((int)qy + 1, 0), W - 1);
        float px = fminf(fmaxf(px_f, 0.0f), (float)(H - 1));
        float py = fminf(fmaxf(py_f, 0.0f), (float)(W - 1));
        float alt = 1.0f + ((float)ltx - px);
        float arb = 1.0f - ((float)rbx - px);
        float blt = 1.0f + ((float)lty - py);
        float brb = 1.0f - ((float)rby - py);
        g0[n] = alt * blt;  i0[n] = ltx * W + lty;
        g1[n] = arb * brb;  i1[n] = rbx * W + rby;
        g2[n] = alt * brb;  i2[n] = ltx * W + rby;
        g3[n] = arb * blt;  i3[n] = rbx * W + lty;
    }

    float acc[16];
#pragma unroll
    for (int o = 0; o < 16; ++o) acc[o] = 0.0f;

    const float* xb = x + b * CIN * HW;
    const float* wg = w + (row4 * 16) * CIN * 9;   // this group's 16 out rows

    for (int chunk = 0; chunk < 4; ++chunk) {
        // ---- Phase A: gather 4 channels per thread into LDS ----
#pragma unroll
        for (int k = 0; k < 4; ++k) {
            int cl = row4 * 4 + k;                 // 0..15
            const float* xc = xb + (chunk * CCHUNK + cl) * HW;
#pragma unroll
            for (int n = 0; n < 9; ++n) {
                xo_s[cl][lpix][n] = g0[n] * xc[i0[n]] + g1[n] * xc[i1[n]]
                                  + g2[n] * xc[i2[n]] + g3[n] * xc[i3[n]];
            }
        }
        __syncthreads();
        // ---- Phase B: 16 channels x 9 taps x 16 outs from LDS ----
#pragma unroll 4
        for (int cl = 0; cl < CCHUNK; ++cl) {
            float v[9];
#pragma unroll
            for (int n = 0; n < 9; ++n) v[n] = xo_s[cl][lpix][n];
            const float* wc = wg + (chunk * CCHUNK + cl) * 9;
#pragma unroll
            for (int o = 0; o < 16; ++o) {
                float a = acc[o];
#pragma unroll
                for (int n = 0; n < 9; ++n)
                    a += wc[o * CIN * 9 + n] * v[n];
                acc[o] = a;
            }
        }
        __syncthreads();
    }

#pragma unroll
    for (int o = 0; o < 16; ++o)
        out[(b * COUT + row4 * 16 + o) * HW + ij] = acc[o];
}

// ---------------------------------------------------------------------------
// Per-channel sum / sumsq — deterministic: one block per channel, direct
// write (no pre-zero, no atomics). stats[0..63]=sum, stats[64..127]=sumsq.
// ---------------------------------------------------------------------------
__global__ __launch_bounds__(1024) void k_stats(const float* __restrict__ y,
                                                float* __restrict__ stats) {
    int c = blockIdx.x;
    float sum = 0.0f, sq = 0.0f;
    for (int b = 0; b < BATCH; ++b) {
        const float* p = y + (b * COUT + c) * HW;
        for (int t = threadIdx.x; t < HW; t += 1024) {
            float v = p[t];
            sum += v;
            sq  += v * v;
        }
    }
#pragma unroll
    for (int d = 32; d > 0; d >>= 1) {
        sum += __shfl_down(sum, d, 64);
        sq  += __shfl_down(sq,  d, 64);
    }
    __shared__ float red[32];                     // 16 waves x 2
    int wave = threadIdx.x >> 6;
    if ((threadIdx.x & 63) == 0) { red[wave] = sum; red[16 + wave] = sq; }
    __syncthreads();
    if (threadIdx.x == 0) {
        float ts = 0.0f, tq = 0.0f;
#pragma unroll
        for (int k = 0; k < 16; ++k) { ts += red[k]; tq += red[16 + k]; }
        stats[c]        = ts;
        stats[COUT + c] = tq;
    }
}

// ---------------------------------------------------------------------------
// Apply BN (biased var) + ReLU.
// ---------------------------------------------------------------------------
__global__ __launch_bounds__(256) void k_bnrelu(const float* __restrict__ y,
                                                const float* __restrict__ stats,
                                                const float* __restrict__ gamma,
                                                const float* __restrict__ beta,
                                                float* __restrict__ out) {
    int t = blockIdx.x * 256 + threadIdx.x;      // grid = B*COUT*HW/256
    int c = (t / HW) % COUT;
    const float inv_m = 1.0f / (float)(BATCH * HW);
    float mu  = stats[c] * inv_m;
    float var = stats[COUT + c] * inv_m - mu * mu;
    float r   = rsqrtf(var + 1e-5f);
    float val = (y[t] - mu) * r * gamma[c] + beta[c];
    out[t] = fmaxf(val, 0.0f);
}

// ---------------------------------------------------------------------------
// Workspace budget (was 58.6 MB with no ws_size check — suspected overrun
// into the harness's pristine input copies caused the round-2 post-timing
// divergence). Now 32.9 MB: stats(1KB) + off(7.2MB) + yraw(25.7MB); the
// stage-1 BN output lives in d_out (safe: final k_bnrelu reads only yraw
// and stats, so overwriting d_out element-wise has no dependence on it).
// ---------------------------------------------------------------------------
extern "C" void kernel_launch(void* const* d_in, const int* in_sizes, int n_in,
                              void* d_out, int out_size, void* d_ws, size_t ws_size,
                              hipStream_t stream) {
    const float* x       = (const float*)d_in[0];
    const float* w_off1  = (const float*)d_in[1];
    const float* b_off1  = (const float*)d_in[2];
    const float* w_conv1 = (const float*)d_in[3];
    const float* gamma1  = (const float*)d_in[4];
    const float* beta1   = (const float*)d_in[5];
    const float* w_off2  = (const float*)d_in[6];
    const float* b_off2  = (const float*)d_in[7];
    const float* w_conv2 = (const float*)d_in[8];
    const float* gamma2  = (const float*)d_in[9];
    const float* beta2   = (const float*)d_in[10];
    float* out = (float*)d_out;

    float* ws    = (float*)d_ws;
    float* stats = ws;                                   // 128 floats (pad 256)
    float* off   = ws + 256;                             // B*18*HW
    float* yraw  = off + (size_t)BATCH * NOFF * HW;      // B*64*HW
    float* y1    = out;                                  // stage-1 BN output

    const int offc_blocks   = (BATCH * HW) / 128;        // 784
    const int deform_blocks = (BATCH * HW) / 64;         // 1568
    const int el_blocks     = (BATCH * COUT * HW) / 256; // 25088

    // ---- stage 1 ----
    k_offconv<<<offc_blocks, 256, 0, stream>>>(x, w_off1, b_off1, off);
    k_deform <<<deform_blocks, 256, 0, stream>>>(x, off, w_conv1, yraw);
    k_stats  <<<COUT, 1024, 0, stream>>>(yraw, stats);
    k_bnrelu <<<el_blocks, 256, 0, stream>>>(yraw, stats, gamma1, beta1, y1);

    // ---- stage 2 ----
    k_offconv<<<offc_blocks, 256, 0, stream>>>(y1, w_off2, b_off2, off);
    k_deform <<<deform_blocks, 256, 0, stream>>>(y1, off, w_conv2, yraw);
    k_stats  <<<COUT, 1024, 0, stream>>>(yraw, stats);
    k_bnrelu <<<el_blocks, 256, 0, stream>>>(yraw, stats, gamma2, beta2, out);
}

// Round 5
// 1163.071 us; speedup vs baseline: 1.6796x; 1.6796x over previous
//
#include <hip/hip_runtime.h>

#define H 224
#define W 224
#define HW (H*W)
#define BATCH 2
#define CIN 64
#define COUT 64
#define NOFF 18
#define K576 576          // K = 64 ch * 9 taps
#define KCHUNK 288        // 32 ch * 9 taps per LDS chunk
#define AROW 296          // 288 + 8 bf16 pad

typedef __attribute__((ext_vector_type(8))) short bf16x8;   // 8 bf16 = 4 VGPRs
typedef __attribute__((ext_vector_type(4))) float f32x4;

__device__ inline short f2bf(float f) {          // RNE float->bf16 bits
    unsigned u = __float_as_uint(f);
    u += 0x7FFF + ((u >> 16) & 1);
    return (short)(u >> 16);
}
__device__ inline float bf2f(short h) {
    return __uint_as_float(((unsigned)(unsigned short)h) << 16);
}
// Split x into hi + lo bf16 (bf16 has fp32 exponent range -> lo never
// subnormal). hi+lo carries ~16-17 mantissa bits; 3-term MFMA product
// (AhBh + AlBh + AhBl) has relative error ~2^-18 — enough to keep the
// offsets on the correct side of the floor/clip discontinuities.
__device__ inline void split_bf(float x, short& hi, short& lo) {
    hi = f2bf(x);
    lo = f2bf(x - bf2f(hi));
}

// ---------------------------------------------------------------------------
// Weight prep: split w_conv (64x576, [n][k] row-major already) and w_off
// (18x576, zero-padded to 32 rows) into hi/lo bf16 planes.
// grid = (64*576 + 32*576)/256 = 216 blocks exactly.
// ---------------------------------------------------------------------------
__global__ __launch_bounds__(256) void k_prepw(const float* __restrict__ wconv,
                                               const float* __restrict__ woff,
                                               short* __restrict__ Wtdh,
                                               short* __restrict__ Wtdl,
                                               short* __restrict__ Wtoh,
                                               short* __restrict__ Wtol) {
    int t = blockIdx.x * 256 + threadIdx.x;
    if (t < COUT * K576) {
        short h, l; split_bf(wconv[t], h, l);
        Wtdh[t] = h; Wtdl[t] = l;
    }
    int t2 = t - COUT * K576;
    if (t2 >= 0 && t2 < 32 * K576) {
        int n = t2 / K576, k = t2 - n * K576;
        float v = (n < NOFF) ? woff[n * K576 + k] : 0.0f;
        short h, l; split_bf(v, h, l);
        Wtoh[t2] = h; Wtol[t2] = l;
    }
}

// ---------------------------------------------------------------------------
// Offset conv as split-bf16 MFMA GEMM. N=32 (18 live), M=64 pixels/block,
// K=576 in 2 chunks. Block = 256 thr = 4 waves. LDS: hi+lo A-tiles (75.8 KB
// -> 2 blocks/CU).
// ---------------------------------------------------------------------------
__global__ __launch_bounds__(256, 2) void k_offconv(const float* __restrict__ x,
                                                    const short* __restrict__ Wtoh,
                                                    const short* __restrict__ Wtol,
                                                    const float* __restrict__ boff,
                                                    float* __restrict__ off) {
    __shared__ __align__(16) short Ah[64 * AROW];   // 37888 B
    __shared__ __align__(16) short Al[64 * AROW];   // 37888 B

    const int tid  = threadIdx.x;
    const int lane = tid & 63;
    const int wave = tid >> 6;
    const int pix  = blockIdx.x * 64 + lane;        // grid = B*HW/64
    const int b    = pix / HW;
    const int ij   = pix - b * HW;
    const int i    = ij / W;
    const int j    = ij - i * W;
    const int l15  = lane & 15;
    const int quad = lane >> 4;
    const int mlds = wave * 16 + l15;

    const float* xb = x + b * CIN * HW;

    f32x4 acc[2];
#pragma unroll
    for (int nt = 0; nt < 2; ++nt) acc[nt] = (f32x4){0.f, 0.f, 0.f, 0.f};

    for (int chunk = 0; chunk < 2; ++chunk) {
        const float* xw = xb + (chunk * 32 + wave * 8) * HW;
        short* arh = &Ah[lane * AROW + wave * 72];   // (wave*8 channels)*9 taps
        short* arl = &Al[lane * AROW + wave * 72];
#pragma unroll
        for (int n = 0; n < 9; ++n) {
            int ii = i + n / 3 - 1, jj = j + n % 3 - 1;
            bool ok = (ii >= 0) & (ii < H) & (jj >= 0) & (jj < W);
            int idx = ok ? ii * W + jj : 0;
#pragma unroll
            for (int cc = 0; cc < 8; ++cc) {
                float v = ok ? xw[cc * HW + idx] : 0.0f;
                short h, l; split_bf(v, h, l);
                arh[cc * 9 + n] = h;
                arl[cc * 9 + n] = l;
            }
        }
        __syncthreads();
        const short* aph = &Ah[mlds * AROW + quad * 8];
        const short* apl = &Al[mlds * AROW + quad * 8];
        const short* bph = Wtoh + l15 * K576 + chunk * KCHUNK + quad * 8;
        const short* bpl = Wtol + l15 * K576 + chunk * KCHUNK + quad * 8;
#pragma unroll
        for (int kt = 0; kt < 9; ++kt) {
            bf16x8 afh = *(const bf16x8*)(aph + kt * 32);
            bf16x8 afl = *(const bf16x8*)(apl + kt * 32);
#pragma unroll
            for (int nt = 0; nt < 2; ++nt) {
                bf16x8 bfh = *(const bf16x8*)(bph + nt * 16 * K576 + kt * 32);
                bf16x8 bfl = *(const bf16x8*)(bpl + nt * 16 * K576 + kt * 32);
                acc[nt] = __builtin_amdgcn_mfma_f32_16x16x32_bf16(afh, bfh, acc[nt], 0, 0, 0);
                acc[nt] = __builtin_amdgcn_mfma_f32_16x16x32_bf16(afl, bfh, acc[nt], 0, 0, 0);
                acc[nt] = __builtin_amdgcn_mfma_f32_16x16x32_bf16(afh, bfl, acc[nt], 0, 0, 0);
            }
        }
        __syncthreads();
    }

    // D layout: m = quad*4 + r (pixel within stripe), n = l15
    const int pst = blockIdx.x * 64 + wave * 16 + quad * 4;
    const int bs  = pst / HW;
    const int ijs = pst - bs * HW;
#pragma unroll
    for (int nt = 0; nt < 2; ++nt) {
        int n = nt * 16 + l15;
        if (n < NOFF) {
            float bi = boff[n];
            float* op = off + (bs * NOFF + n) * HW + ijs;
#pragma unroll
            for (int r = 0; r < 4; ++r) op[r] = acc[nt][r] + bi;
        }
    }
}

// ---------------------------------------------------------------------------
// Deformable sampling + conv as split-bf16 MFMA GEMM. M=64 px, N=64 outs,
// K=576 (2 chunks). Bilinear sampled in fp32, split into hi/lo LDS tiles.
// ---------------------------------------------------------------------------
__global__ __launch_bounds__(256, 2) void k_deform(const float* __restrict__ x,
                                                   const float* __restrict__ off,
                                                   const short* __restrict__ Wtdh,
                                                   const short* __restrict__ Wtdl,
                                                   float* __restrict__ out) {
    __shared__ __align__(16) short Ah[64 * AROW];   // 37888 B
    __shared__ __align__(16) short Al[64 * AROW];   // 37888 B

    const int tid  = threadIdx.x;
    const int lane = tid & 63;
    const int wave = tid >> 6;
    const int pix  = blockIdx.x * 64 + lane;
    const int b    = pix / HW;
    const int ij   = pix - b * HW;
    const int i    = ij / W;
    const int j    = ij - i * W;
    const int l15  = lane & 15;
    const int quad = lane >> 4;
    const int mlds = wave * 16 + l15;

    const float* offp = off + b * NOFF * HW + ij;
    const float* xb   = x + b * CIN * HW;

    f32x4 acc[4];
#pragma unroll
    for (int nt = 0; nt < 4; ++nt) acc[nt] = (f32x4){0.f, 0.f, 0.f, 0.f};

    for (int chunk = 0; chunk < 2; ++chunk) {
        const float* xw = xb + (chunk * 32 + wave * 8) * HW;
        short* arh = &Ah[lane * AROW + wave * 72];
        short* arl = &Al[lane * AROW + wave * 72];
#pragma unroll
        for (int n = 0; n < 9; ++n) {
            float px_f = (float)(i + n / 3) + offp[n * HW];
            float py_f = (float)(j + n % 3) + offp[(9 + n) * HW];
            float qx = floorf(px_f), qy = floorf(py_f);
            int ltx = min(max((int)qx, 0), H - 1);
            int lty = min(max((int)qy, 0), W - 1);
            int rbx = min(max((int)qx + 1, 0), H - 1);
            int rby = min(max((int)qy + 1, 0), W - 1);
            float px = fminf(fmaxf(px_f, 0.0f), (float)(H - 1));
            float py = fminf(fmaxf(py_f, 0.0f), (float)(W - 1));
            float alt = 1.0f + ((float)ltx - px);
            float arb = 1.0f - ((float)rbx - px);
            float blt = 1.0f + ((float)lty - py);
            float brb = 1.0f - ((float)rby - py);
            float g0 = alt * blt; int i0 = ltx * W + lty;
            float g1 = arb * brb; int i1 = rbx * W + rby;
            float g2 = alt * brb; int i2 = ltx * W + rby;
            float g3 = arb * blt; int i3 = rbx * W + lty;
#pragma unroll
            for (int cc = 0; cc < 8; ++cc) {
                const float* xc = xw + cc * HW;
                float v = g0 * xc[i0] + g1 * xc[i1] + g2 * xc[i2] + g3 * xc[i3];
                short h, l; split_bf(v, h, l);
                arh[cc * 9 + n] = h;
                arl[cc * 9 + n] = l;
            }
        }
        __syncthreads();
        const short* aph = &Ah[mlds * AROW + quad * 8];
        const short* apl = &Al[mlds * AROW + quad * 8];
        const short* bph = Wtdh + l15 * K576 + chunk * KCHUNK + quad * 8;
        const short* bpl = Wtdl + l15 * K576 + chunk * KCHUNK + quad * 8;
#pragma unroll
        for (int kt = 0; kt < 9; ++kt) {
            bf16x8 afh = *(const bf16x8*)(aph + kt * 32);
            bf16x8 afl = *(const bf16x8*)(apl + kt * 32);
#pragma unroll
            for (int nt = 0; nt < 4; ++nt) {
                bf16x8 bfh = *(const bf16x8*)(bph + nt * 16 * K576 + kt * 32);
                bf16x8 bfl = *(const bf16x8*)(bpl + nt * 16 * K576 + kt * 32);
                acc[nt] = __builtin_amdgcn_mfma_f32_16x16x32_bf16(afh, bfh, acc[nt], 0, 0, 0);
                acc[nt] = __builtin_amdgcn_mfma_f32_16x16x32_bf16(afl, bfh, acc[nt], 0, 0, 0);
                acc[nt] = __builtin_amdgcn_mfma_f32_16x16x32_bf16(afh, bfl, acc[nt], 0, 0, 0);
            }
        }
        __syncthreads();
    }

    const int pst = blockIdx.x * 64 + wave * 16 + quad * 4;
    const int bs  = pst / HW;
    const int ijs = pst - bs * HW;
#pragma unroll
    for (int nt = 0; nt < 4; ++nt) {
        float* op = out + (bs * COUT + nt * 16 + l15) * HW + ijs;
#pragma unroll
        for (int r = 0; r < 4; ++r) op[r] = acc[nt][r];
    }
}

// ---------------------------------------------------------------------------
// Per-channel partial sum/sumsq: grid = 64 ch x 8 segs, deterministic writes.
// ---------------------------------------------------------------------------
__global__ __launch_bounds__(256) void k_stats(const float* __restrict__ y,
                                               float* __restrict__ part) {
    int c = blockIdx.x >> 3;
    int s = blockIdx.x & 7;
    const int seg = HW / 8;   // 6272
    float sum = 0.f, sq = 0.f;
    for (int b = 0; b < BATCH; ++b) {
        const float* p = y + (b * COUT + c) * HW + s * seg;
        for (int t = threadIdx.x; t < seg; t += 256) {
            float v = p[t]; sum += v; sq += v * v;
        }
    }
#pragma unroll
    for (int d = 32; d > 0; d >>= 1) {
        sum += __shfl_down(sum, d, 64);
        sq  += __shfl_down(sq,  d, 64);
    }
    __shared__ float red[8];
    int wv = threadIdx.x >> 6;
    if ((threadIdx.x & 63) == 0) { red[wv] = sum; red[4 + wv] = sq; }
    __syncthreads();
    if (threadIdx.x == 0) {
        part[c * 8 + s]       = red[0] + red[1] + red[2] + red[3];
        part[512 + c * 8 + s] = red[4] + red[5] + red[6] + red[7];
    }
}

// ---------------------------------------------------------------------------
// BN (biased var) + ReLU. Each block maps to a single channel (HW%256==0).
// ---------------------------------------------------------------------------
__global__ __launch_bounds__(256) void k_bnrelu(const float* __restrict__ y,
                                                const float* __restrict__ part,
                                                const float* __restrict__ gamma,
                                                const float* __restrict__ beta,
                                                float* __restrict__ out) {
    int t0 = blockIdx.x * 256;
    int c  = (t0 / HW) % COUT;            // block-uniform
    __shared__ float sm[2];
    if (threadIdx.x == 0) {
        float s = 0.f, q = 0.f;
#pragma unroll
        for (int k = 0; k < 8; ++k) { s += part[c * 8 + k]; q += part[512 + c * 8 + k]; }
        const float inv_m = 1.0f / (float)(BATCH * HW);
        float mu    = s * inv_m;
        float var   = q * inv_m - mu * mu;
        float scale = rsqrtf(var + 1e-5f) * gamma[c];
        sm[0] = scale;
        sm[1] = beta[c] - mu * scale;
    }
    __syncthreads();
    int t = t0 + threadIdx.x;
    float val = fmaf(y[t], sm[0], sm[1]);
    out[t] = fmaxf(val, 0.0f);
}

// ---------------------------------------------------------------------------
// Workspace: Wtdh/Wtdl 2x73728 + Wtoh/Wtol 2x36864 = 221184 B + part 4096 +
// off 7.23 MB + yraw 25.7 MB = ~31.6 MB (round-3 budget passed at ~33 MB).
// Stage-1 BN output lives in d_out.
// ---------------------------------------------------------------------------
extern "C" void kernel_launch(void* const* d_in, const int* in_sizes, int n_in,
                              void* d_out, int out_size, void* d_ws, size_t ws_size,
                              hipStream_t stream) {
    const float* x       = (const float*)d_in[0];
    const float* w_off1  = (const float*)d_in[1];
    const float* b_off1  = (const float*)d_in[2];
    const float* w_conv1 = (const float*)d_in[3];
    const float* gamma1  = (const float*)d_in[4];
    const float* beta1   = (const float*)d_in[5];
    const float* w_off2  = (const float*)d_in[6];
    const float* b_off2  = (const float*)d_in[7];
    const float* w_conv2 = (const float*)d_in[8];
    const float* gamma2  = (const float*)d_in[9];
    const float* beta2   = (const float*)d_in[10];
    float* out = (float*)d_out;

    char*  wsb  = (char*)d_ws;
    short* Wtdh = (short*)wsb;                          // 73728 B
    short* Wtdl = (short*)(wsb + 73728);                // 73728 B
    short* Wtoh = (short*)(wsb + 147456);               // 36864 B
    short* Wtol = (short*)(wsb + 184320);               // 36864 B
    float* part = (float*)(wsb + 221184);               // 4096 B
    float* off  = (float*)(wsb + 225280);               // B*18*HW
    float* yraw = off + (size_t)BATCH * NOFF * HW;      // B*64*HW
    float* y1   = out;

    const int conv_blocks = (BATCH * HW) / 64;          // 1568
    const int el_blocks   = (BATCH * COUT * HW) / 256;  // 25088

    // ---- stage 1 ----
    k_prepw  <<<216, 256, 0, stream>>>(w_conv1, w_off1, Wtdh, Wtdl, Wtoh, Wtol);
    k_offconv<<<conv_blocks, 256, 0, stream>>>(x, Wtoh, Wtol, b_off1, off);
    k_deform <<<conv_blocks, 256, 0, stream>>>(x, off, Wtdh, Wtdl, yraw);
    k_stats  <<<512, 256, 0, stream>>>(yraw, part);
    k_bnrelu <<<el_blocks, 256, 0, stream>>>(yraw, part, gamma1, beta1, y1);

    // ---- stage 2 ----
    k_prepw  <<<216, 256, 0, stream>>>(w_conv2, w_off2, Wtdh, Wtdl, Wtoh, Wtol);
    k_offconv<<<conv_blocks, 256, 0, stream>>>(y1, Wtoh, Wtol, b_off2, off);
    k_deform <<<conv_blocks, 256, 0, stream>>>(y1, off, Wtdh, Wtdl, yraw);
    k_stats  <<<512, 256, 0, stream>>>(yraw, part);
    k_bnrelu <<<el_blocks, 256, 0, stream>>>(yraw, part, gamma2, beta2, out);
}

// Round 7
// 856.220 us; speedup vs baseline: 2.2815x; 1.3584x over previous
//
#include <hip/hip_runtime.h>

#define H 224
#define W 224
#define HW (H*W)
#define BATCH 2
#define CIN 64
#define COUT 64
#define NOFF 18
#define K576 576          // K = 64 ch * 9 taps
#define KCHUNK 288        // 32 ch * 9 taps per chunk (k = tap*32 + cc)
#define AROW 296          // 288 + 8 bf16 pad (592 B rows, 16B-aligned)
#define OFFS 20           // off stored NHWC with stride 20 (18 live, f4-aligned)

typedef __attribute__((ext_vector_type(8))) short bf16x8;
typedef __attribute__((ext_vector_type(4))) short s16x4;
typedef __attribute__((ext_vector_type(4))) float f32x4;

__device__ inline short f2bf(float f) {
    unsigned u = __float_as_uint(f);
    u += 0x7FFF + ((u >> 16) & 1);
    return (short)(u >> 16);
}
__device__ inline float bf2f(short h) {
    return __uint_as_float(((unsigned)(unsigned short)h) << 16);
}
__device__ inline void split_bf(float x, short& hi, short& lo) {
    hi = f2bf(x);
    lo = f2bf(x - bf2f(hi));
}
// 4-wide split into packed vectors (no references into ext_vector elements).
__device__ inline void split_bf4(float a, float b, float c, float d,
                                 s16x4& h4, s16x4& l4) {
    short h0, l0, h1, l1, h2, l2, h3, l3;
    split_bf(a, h0, l0); split_bf(b, h1, l1);
    split_bf(c, h2, l2); split_bf(d, h3, l3);
    h4 = (s16x4){h0, h1, h2, h3};
    l4 = (s16x4){l0, l1, l2, l3};
}

// ---------------------------------------------------------------------------
// Weight prep: split into hi/lo bf16 AND permute K from c*9+tap to
// chunk*288 + tap*32 + cc  (so sampled NHWC channel runs are contiguous in k).
// ---------------------------------------------------------------------------
__global__ __launch_bounds__(256) void k_prepw(const float* __restrict__ wconv,
                                               const float* __restrict__ woff,
                                               short* __restrict__ Wtdh,
                                               short* __restrict__ Wtdl,
                                               short* __restrict__ Wtoh,
                                               short* __restrict__ Wtol) {
    int t = blockIdx.x * 256 + threadIdx.x;
    if (t < COUT * K576) {
        int n = t / K576, kp = t - n * K576;
        int chunk = kp / KCHUNK, r = kp - chunk * KCHUNK;
        int tap = r >> 5, cc = r & 31;
        int c = chunk * 32 + cc;
        short h, l; split_bf(wconv[n * K576 + c * 9 + tap], h, l);
        Wtdh[t] = h; Wtdl[t] = l;
    }
    int t2 = t - COUT * K576;
    if (t2 >= 0 && t2 < 32 * K576) {
        int n = t2 / K576, kp = t2 - n * K576;
        int chunk = kp / KCHUNK, r = kp - chunk * KCHUNK;
        int tap = r >> 5, cc = r & 31;
        int c = chunk * 32 + cc;
        float v = (n < NOFF) ? woff[n * K576 + c * 9 + tap] : 0.0f;
        short h, l; split_bf(v, h, l);
        Wtoh[t2] = h; Wtol[t2] = l;
    }
}

// ---------------------------------------------------------------------------
// x NCHW -> NHWC. Tile 64 px x 64 ch via LDS.  grid = B*HW/64.
// ---------------------------------------------------------------------------
__global__ __launch_bounds__(256) void k_transpose(const float* __restrict__ x,
                                                   float* __restrict__ xT) {
    __shared__ float Lt[64][65];
    int blk = blockIdx.x, t = threadIdx.x;
    int px0 = blk * 64;
    int b   = px0 / HW;
    int ij0 = px0 - b * HW;
    int lane = t & 63, g = t >> 6;
#pragma unroll
    for (int r = 0; r < 16; ++r) {
        int c = r * 4 + g;
        Lt[c][lane] = x[(b * CIN + c) * HW + ij0 + lane];
    }
    __syncthreads();
#pragma unroll
    for (int r = 0; r < 16; ++r) {
        int px = r * 4 + g;
        xT[((size_t)(b * HW + ij0 + px)) * 64 + lane] = Lt[lane][px];
    }
}

// ---------------------------------------------------------------------------
// Offset conv (dense 3x3, pad 1) as split-bf16 MFMA GEMM on NHWC input.
// M=32 px/block, N=32 (18 live), K=576 in 2 chunks. 256 thr = 4 waves.
// ---------------------------------------------------------------------------
__global__ __launch_bounds__(256, 4) void k_offconv(const float* __restrict__ xT,
                                                    const short* __restrict__ Wtoh,
                                                    const short* __restrict__ Wtol,
                                                    const float* __restrict__ boff,
                                                    float* __restrict__ off) {
    __shared__ __align__(16) char smem[2 * 32 * AROW * 2];  // 37888 B
    short* Ah = (short*)smem;
    short* Al = Ah + 32 * AROW;

    const int t    = threadIdx.x;
    const int lane = t & 63;
    const int wave = t >> 6;
    const int px0  = blockIdx.x * 32;          // grid = B*HW/32
    const int b    = px0 / HW;
    const int ij0  = px0 - b * HW;
    const int spx  = t & 31;                   // sampling: pixel
    const int cg   = t >> 5;                   // sampling: 8 groups of 4 ch
    const int ij   = ij0 + spx;
    const int i    = ij / W;
    const int j    = ij - i * W;
    const int l15  = lane & 15;
    const int quad = lane >> 4;
    const int mtb  = wave >> 1;                // compute: m-tile 0..1
    const int ntb  = wave & 1;                 // compute: n-tile 0..1

    const float* xb = xT + (size_t)(b * HW) * 64;

    f32x4 acc = (f32x4){0.f, 0.f, 0.f, 0.f};

    for (int chunk = 0; chunk < 2; ++chunk) {
        const int ch = chunk * 32 + cg * 4;
        short* wrh = &Ah[spx * AROW + cg * 4];
        short* wrl = &Al[spx * AROW + cg * 4];
#pragma unroll
        for (int n = 0; n < 9; ++n) {
            int ii = i + n / 3 - 1, jj = j + n % 3 - 1;
            bool ok = (ii >= 0) & (ii < H) & (jj >= 0) & (jj < W);
            float4 v = make_float4(0.f, 0.f, 0.f, 0.f);
            if (ok) v = *(const float4*)(xb + (size_t)(ii * W + jj) * 64 + ch);
            s16x4 h4, l4;
            split_bf4(v.x, v.y, v.z, v.w, h4, l4);
            *(s16x4*)(wrh + n * 32) = h4;
            *(s16x4*)(wrl + n * 32) = l4;
        }
        __syncthreads();
        const short* aph = &Ah[(mtb * 16 + l15) * AROW + quad * 8];
        const short* apl = &Al[(mtb * 16 + l15) * AROW + quad * 8];
        const short* bph = Wtoh + (ntb * 16 + l15) * K576 + chunk * KCHUNK + quad * 8;
        const short* bpl = Wtol + (ntb * 16 + l15) * K576 + chunk * KCHUNK + quad * 8;
#pragma unroll
        for (int kt = 0; kt < 9; ++kt) {
            bf16x8 afh = *(const bf16x8*)(aph + kt * 32);
            bf16x8 afl = *(const bf16x8*)(apl + kt * 32);
            bf16x8 bfh = *(const bf16x8*)(bph + kt * 32);
            bf16x8 bfl = *(const bf16x8*)(bpl + kt * 32);
            acc = __builtin_amdgcn_mfma_f32_16x16x32_bf16(afh, bfh, acc, 0, 0, 0);
            acc = __builtin_amdgcn_mfma_f32_16x16x32_bf16(afl, bfh, acc, 0, 0, 0);
            acc = __builtin_amdgcn_mfma_f32_16x16x32_bf16(afh, bfl, acc, 0, 0, 0);
        }
        __syncthreads();
    }

    // Repack: Ld[px][20] then full-line-ish stores.
    float* Ld = (float*)smem;
    int n = ntb * 16 + l15;                    // 0..31
    if (n < OFFS) {
        float bi = (n < NOFF) ? boff[n] : 0.0f;
        int pxr = mtb * 16 + quad * 4;
#pragma unroll
        for (int r = 0; r < 4; ++r)
            Ld[(pxr + r) * OFFS + n] = acc[r] + bi;
    }
    __syncthreads();
    {
        int px = t >> 3, c4 = t & 7;
        if (c4 < 5) {
            float4 v = *(float4*)&Ld[px * OFFS + c4 * 4];
            *(float4*)(off + (size_t)(b * HW + ij0 + px) * OFFS + c4 * 4) = v;
        }
    }
}

// ---------------------------------------------------------------------------
// Deformable sampling + conv as split-bf16 MFMA GEMM on NHWC input.
// M=32 px, N=64, K=576 (2 chunks). OUT_NHWC: stage-1 NHWC; else NCHW.
// ---------------------------------------------------------------------------
template <bool OUT_NHWC>
__global__ __launch_bounds__(256, 4) void k_deform(const float* __restrict__ xT,
                                                   const float* __restrict__ off,
                                                   const short* __restrict__ Wtdh,
                                                   const short* __restrict__ Wtdl,
                                                   float* __restrict__ out) {
    __shared__ __align__(16) char smem[2 * 32 * AROW * 2];  // 37888 B
    short* Ah = (short*)smem;
    short* Al = Ah + 32 * AROW;

    const int t    = threadIdx.x;
    const int lane = t & 63;
    const int wave = t >> 6;
    const int px0  = blockIdx.x * 32;          // grid = B*HW/32
    const int b    = px0 / HW;
    const int ij0  = px0 - b * HW;
    const int spx  = t & 31;
    const int cg   = t >> 5;
    const int ij   = ij0 + spx;
    const int i    = ij / W;
    const int j    = ij - i * W;
    const int l15  = lane & 15;
    const int quad = lane >> 4;
    const int mtb  = wave >> 1;                // m-tile 0..1
    const int ntb0 = (wave & 1) * 2;           // n-tiles {0,1} or {2,3}

    const float* xb = xT + (size_t)(b * HW) * 64;

    // load 18 offsets for this pixel (vectorized, stride-20 layout)
    float offa[20];
#pragma unroll
    for (int k = 0; k < 5; ++k)
        *(float4*)&offa[k * 4] = *(const float4*)(off + (size_t)(b * HW + ij) * OFFS + k * 4);

    f32x4 acc[2];
    acc[0] = (f32x4){0.f, 0.f, 0.f, 0.f};
    acc[1] = (f32x4){0.f, 0.f, 0.f, 0.f};

    for (int chunk = 0; chunk < 2; ++chunk) {
        const int ch = chunk * 32 + cg * 4;
        short* wrh = &Ah[spx * AROW + cg * 4];
        short* wrl = &Al[spx * AROW + cg * 4];
#pragma unroll
        for (int n = 0; n < 9; ++n) {
            float px_f = (float)(i + n / 3) + offa[n];
            float py_f = (float)(j + n % 3) + offa[9 + n];
            float qx = floorf(px_f), qy = floorf(py_f);
            int ltx = min(max((int)qx, 0), H - 1);
            int lty = min(max((int)qy, 0), W - 1);
            int rbx = min(max((int)qx + 1, 0), H - 1);
            int rby = min(max((int)qy + 1, 0), W - 1);
            float px = fminf(fmaxf(px_f, 0.0f), (float)(H - 1));
            float py = fminf(fmaxf(py_f, 0.0f), (float)(W - 1));
            float alt = 1.0f + ((float)ltx - px);
            float arb = 1.0f - ((float)rbx - px);
            float blt = 1.0f + ((float)lty - py);
            float brb = 1.0f - ((float)rby - py);
            float g0 = alt * blt, g1 = arb * brb, g2 = alt * brb, g3 = arb * blt;
            const float4 v0 = *(const float4*)(xb + (size_t)(ltx * W + lty) * 64 + ch);
            const float4 v1 = *(const float4*)(xb + (size_t)(rbx * W + rby) * 64 + ch);
            const float4 v2 = *(const float4*)(xb + (size_t)(ltx * W + rby) * 64 + ch);
            const float4 v3 = *(const float4*)(xb + (size_t)(rbx * W + lty) * 64 + ch);
            float s0 = g0 * v0.x + g1 * v1.x + g2 * v2.x + g3 * v3.x;
            float s1 = g0 * v0.y + g1 * v1.y + g2 * v2.y + g3 * v3.y;
            float s2 = g0 * v0.z + g1 * v1.z + g2 * v2.z + g3 * v3.z;
            float s3 = g0 * v0.w + g1 * v1.w + g2 * v2.w + g3 * v3.w;
            s16x4 h4, l4;
            split_bf4(s0, s1, s2, s3, h4, l4);
            *(s16x4*)(wrh + n * 32) = h4;
            *(s16x4*)(wrl + n * 32) = l4;
        }
        __syncthreads();
        const short* aph = &Ah[(mtb * 16 + l15) * AROW + quad * 8];
        const short* apl = &Al[(mtb * 16 + l15) * AROW + quad * 8];
        const short* bh0 = Wtdh + (ntb0 * 16 + l15) * K576 + chunk * KCHUNK + quad * 8;
        const short* bl0 = Wtdl + (ntb0 * 16 + l15) * K576 + chunk * KCHUNK + quad * 8;
#pragma unroll
        for (int kt = 0; kt < 9; ++kt) {
            bf16x8 afh = *(const bf16x8*)(aph + kt * 32);
            bf16x8 afl = *(const bf16x8*)(apl + kt * 32);
#pragma unroll
            for (int nt = 0; nt < 2; ++nt) {
                bf16x8 bfh = *(const bf16x8*)(bh0 + nt * 16 * K576 + kt * 32);
                bf16x8 bfl = *(const bf16x8*)(bl0 + nt * 16 * K576 + kt * 32);
                acc[nt] = __builtin_amdgcn_mfma_f32_16x16x32_bf16(afh, bfh, acc[nt], 0, 0, 0);
                acc[nt] = __builtin_amdgcn_mfma_f32_16x16x32_bf16(afl, bfh, acc[nt], 0, 0, 0);
                acc[nt] = __builtin_amdgcn_mfma_f32_16x16x32_bf16(afh, bfl, acc[nt], 0, 0, 0);
            }
        }
        __syncthreads();
    }

    float* Ld = (float*)smem;
    if (OUT_NHWC) {
        // Ld[px][72]: px-major, channel-contiguous reads
        int pxr = mtb * 16 + quad * 4;
#pragma unroll
        for (int nt = 0; nt < 2; ++nt) {
            int c = (ntb0 + nt) * 16 + l15;
#pragma unroll
            for (int r = 0; r < 4; ++r)
                Ld[(pxr + r) * 72 + c] = acc[nt][r];
        }
        __syncthreads();
#pragma unroll
        for (int r = 0; r < 2; ++r) {
            int px = (t >> 4) + r * 16, c4 = t & 15;
            float4 v = *(float4*)&Ld[px * 72 + c4 * 4];
            *(float4*)(out + (size_t)(b * HW + ij0 + px) * 64 + c4 * 4) = v;
        }
    } else {
        // Ld[c][36]: channel-major, pixel-contiguous reads -> full NCHW lines
        int pxr = mtb * 16 + quad * 4;
#pragma unroll
        for (int nt = 0; nt < 2; ++nt) {
            int c = (ntb0 + nt) * 16 + l15;
#pragma unroll
            for (int r = 0; r < 4; ++r)
                Ld[c * 36 + pxr + r] = acc[nt][r];
        }
        __syncthreads();
#pragma unroll
        for (int cc = 0; cc < 2; ++cc) {
            int c = cc * 32 + (t >> 3), p4 = t & 7;
            float4 v = *(float4*)&Ld[c * 36 + p4 * 4];
            *(float4*)(out + (size_t)(b * COUT + c) * HW + ij0 + p4 * 4) = v;
        }
    }
}

// ---------------------------------------------------------------------------
// Stats on NHWC: grid 196 blocks x 512 px. part[c*256+blk]=sum,
// part[16384 + c*256+blk]=sumsq.
// ---------------------------------------------------------------------------
__global__ __launch_bounds__(256) void k_stats_nhwc(const float* __restrict__ y,
                                                    float* __restrict__ part) {
    __shared__ float Ls[16 * 64], Lq[16 * 64];
    int t = threadIdx.x, blk = blockIdx.x;
    int c4 = (t & 15) * 4, sub = t >> 4;
    float4 s4 = make_float4(0.f, 0.f, 0.f, 0.f), q4 = s4;
    const float* p = y + ((size_t)blk * 512 + sub * 32) * 64 + c4;
    for (int k = 0; k < 32; ++k) {
        float4 v = *(const float4*)(p + (size_t)k * 64);
        s4.x += v.x; s4.y += v.y; s4.z += v.z; s4.w += v.w;
        q4.x += v.x * v.x; q4.y += v.y * v.y; q4.z += v.z * v.z; q4.w += v.w * v.w;
    }
    *(float4*)&Ls[sub * 64 + c4] = s4;
    *(float4*)&Lq[sub * 64 + c4] = q4;
    __syncthreads();
    if (t < 64) {
        float s = 0.f, q = 0.f;
#pragma unroll
        for (int k = 0; k < 16; ++k) { s += Ls[k * 64 + t]; q += Lq[k * 64 + t]; }
        part[t * 256 + blk]         = s;
        part[16384 + t * 256 + blk] = q;
    }
}

// ---------------------------------------------------------------------------
// Stats on NCHW: grid = 64 ch x 7 segs (HW = 7 * 7168).
// ---------------------------------------------------------------------------
__global__ __launch_bounds__(256) void k_stats_nchw(const float* __restrict__ y,
                                                    float* __restrict__ part) {
    int c = blockIdx.x / 7, s = blockIdx.x % 7;
    int t = threadIdx.x;
    float4 s4 = make_float4(0.f, 0.f, 0.f, 0.f), q4 = s4;
    for (int b = 0; b < BATCH; ++b) {
        const float* p = y + (size_t)(b * COUT + c) * HW + s * 7168 + t * 4;
        for (int k = 0; k < 7; ++k) {
            float4 v = *(const float4*)(p + k * 1024);
            s4.x += v.x; s4.y += v.y; s4.z += v.z; s4.w += v.w;
            q4.x += v.x * v.x; q4.y += v.y * v.y; q4.z += v.z * v.z; q4.w += v.w * v.w;
        }
    }
    float sum = s4.x + s4.y + s4.z + s4.w;
    float sq  = q4.x + q4.y + q4.z + q4.w;
#pragma unroll
    for (int d = 32; d > 0; d >>= 1) {
        sum += __shfl_down(sum, d, 64);
        sq  += __shfl_down(sq,  d, 64);
    }
    __shared__ float red[8];
    int wv = t >> 6;
    if ((t & 63) == 0) { red[wv] = sum; red[4 + wv] = sq; }
    __syncthreads();
    if (t == 0) {
        part[c * 256 + s]         = red[0] + red[1] + red[2] + red[3];
        part[16384 + c * 256 + s] = red[4] + red[5] + red[6] + red[7];
    }
}

// ---------------------------------------------------------------------------
// Combine partials -> per-channel scale/shift.  ss[c]=scale, ss[64+c]=shift.
// ---------------------------------------------------------------------------
__global__ __launch_bounds__(256) void k_stats2(const float* __restrict__ part,
                                                int nseg,
                                                const float* __restrict__ gamma,
                                                const float* __restrict__ beta,
                                                float* __restrict__ ss) {
    __shared__ float R[2][4][64];
    int t = threadIdx.x, c = t & 63, g = t >> 6;
    float s = 0.f, q = 0.f;
    for (int k = g; k < nseg; k += 4) {
        s += part[c * 256 + k];
        q += part[16384 + c * 256 + k];
    }
    R[0][g][c] = s; R[1][g][c] = q;
    __syncthreads();
    if (t < 64) {
        float ts = R[0][0][t] + R[0][1][t] + R[0][2][t] + R[0][3][t];
        float tq = R[1][0][t] + R[1][1][t] + R[1][2][t] + R[1][3][t];
        const float inv_m = 1.0f / (float)(BATCH * HW);
        float mu    = ts * inv_m;
        float var   = tq * inv_m - mu * mu;
        float scale = rsqrtf(var + 1e-5f) * gamma[t];
        ss[t]      = scale;
        ss[64 + t] = beta[t] - mu * scale;
    }
}

// ---------------------------------------------------------------------------
// BN+ReLU on NHWC (stage 1): y (NHWC) -> out (NHWC). f4, grid = B*HW*64/1024.
// ---------------------------------------------------------------------------
__global__ __launch_bounds__(256) void k_bnrelu_nhwc(const float* __restrict__ y,
                                                     const float* __restrict__ ss,
                                                     float* __restrict__ out) {
    size_t idx = ((size_t)blockIdx.x * 256 + threadIdx.x) * 4;
    int c4 = (int)(idx & 63);
    float4 sc = *(const float4*)(ss + c4);
    float4 sh = *(const float4*)(ss + 64 + c4);
    float4 v  = *(const float4*)(y + idx);
    float4 r;
    r.x = fmaxf(fmaf(v.x, sc.x, sh.x), 0.f);
    r.y = fmaxf(fmaf(v.y, sc.y, sh.y), 0.f);
    r.z = fmaxf(fmaf(v.z, sc.z, sh.z), 0.f);
    r.w = fmaxf(fmaf(v.w, sc.w, sh.w), 0.f);
    *(float4*)(out + idx) = r;
}

// ---------------------------------------------------------------------------
// BN+ReLU on NCHW, IN-PLACE (stage 2). Each block = 1024 elems in one channel
// (HW = 49*1024). grid = B*64*49.
// ---------------------------------------------------------------------------
__global__ __launch_bounds__(256) void k_bnrelu_nchw(float* __restrict__ y,
                                                     const float* __restrict__ ss) {
    int c = (blockIdx.x / 49) % COUT;      // block-uniform
    float scale = ss[c], shift = ss[64 + c];
    size_t idx = ((size_t)blockIdx.x * 1024) + threadIdx.x * 4;
    float4 v = *(const float4*)(y + idx);
    float4 r;
    r.x = fmaxf(fmaf(v.x, scale, shift), 0.f);
    r.y = fmaxf(fmaf(v.y, scale, shift), 0.f);
    r.z = fmaxf(fmaf(v.z, scale, shift), 0.f);
    r.w = fmaxf(fmaf(v.w, scale, shift), 0.f);
    *(float4*)(y + idx) = r;
}

// ---------------------------------------------------------------------------
// Workspace (34.1 MB): weights 216 KB | part 128 KB | ss 512 B |
// bufC(off20) 8.0 MB | bufB(xT / y1 NHWC) 25.7 MB.
// d_out triple-duty: yraw1 (NHWC) -> yraw2 (NCHW) -> final (in-place BN).
// ---------------------------------------------------------------------------
extern "C" void kernel_launch(void* const* d_in, const int* in_sizes, int n_in,
                              void* d_out, int out_size, void* d_ws, size_t ws_size,
                              hipStream_t stream) {
    const float* x       = (const float*)d_in[0];
    const float* w_off1  = (const float*)d_in[1];
    const float* b_off1  = (const float*)d_in[2];
    const float* w_conv1 = (const float*)d_in[3];
    const float* gamma1  = (const float*)d_in[4];
    const float* beta1   = (const float*)d_in[5];
    const float* w_off2  = (const float*)d_in[6];
    const float* b_off2  = (const float*)d_in[7];
    const float* w_conv2 = (const float*)d_in[8];
    const float* gamma2  = (const float*)d_in[9];
    const float* beta2   = (const float*)d_in[10];
    float* out = (float*)d_out;

    char*  wsb  = (char*)d_ws;
    short* Wtdh = (short*)wsb;                           // 73728
    short* Wtdl = (short*)(wsb + 73728);                 // 73728
    short* Wtoh = (short*)(wsb + 147456);                // 36864
    short* Wtol = (short*)(wsb + 184320);                // 36864
    float* part = (float*)(wsb + 221184);                // 131072
    float* ss   = (float*)(wsb + 352256);                // 512
    float* bufC = (float*)(wsb + 352768);                // off20: 8028160
    float* bufB = (float*)(wsb + 8380928);               // xT/y1: 25690112

    const int conv_blocks = (BATCH * HW) / 32;           // 3136
    const int tp_blocks   = (BATCH * HW) / 64;           // 1568
    const int bn_blocks   = (BATCH * COUT * HW) / 1024;  // 6272

    // ---- stage 1 ----
    k_prepw      <<<216, 256, 0, stream>>>(w_conv1, w_off1, Wtdh, Wtdl, Wtoh, Wtol);
    k_transpose  <<<tp_blocks, 256, 0, stream>>>(x, bufB);
    k_offconv    <<<conv_blocks, 256, 0, stream>>>(bufB, Wtoh, Wtol, b_off1, bufC);
    k_deform<true><<<conv_blocks, 256, 0, stream>>>(bufB, bufC, Wtdh, Wtdl, out);
    k_stats_nhwc <<<196, 256, 0, stream>>>(out, part);
    k_stats2     <<<1, 256, 0, stream>>>(part, 196, gamma1, beta1, ss);
    k_bnrelu_nhwc<<<bn_blocks, 256, 0, stream>>>(out, ss, bufB);   // y1 (NHWC)

    // ---- stage 2 ----
    k_prepw      <<<216, 256, 0, stream>>>(w_conv2, w_off2, Wtdh, Wtdl, Wtoh, Wtol);
    k_offconv    <<<conv_blocks, 256, 0, stream>>>(bufB, Wtoh, Wtol, b_off2, bufC);
    k_deform<false><<<conv_blocks, 256, 0, stream>>>(bufB, bufC, Wtdh, Wtdl, out);
    k_stats_nchw <<<448, 256, 0, stream>>>(out, part);
    k_stats2     <<<1, 256, 0, stream>>>(part, 7, gamma2, beta2, ss);
    k_bnrelu_nchw<<<bn_blocks, 256, 0, stream>>>(out, ss);         // in-place
}

// Round 8
// 845.385 us; speedup vs baseline: 2.3107x; 1.0128x over previous
//
#include <hip/hip_runtime.h>

#define H 224
#define W 224
#define HW (H*W)
#define BATCH 2
#define CIN 64
#define COUT 64
#define NOFF 18
#define K576 576          // K = 64 ch * 9 taps
#define KCHUNK 288        // 32 ch * 9 taps per chunk (k = tap*32 + cc)
#define AROW 296          // 288 + 8 bf16 pad (592 B rows, 16B-aligned)
#define OFFS 20           // off stored NHWC with stride 20 (18 live, f4-aligned)
#define NBLK (BATCH*HW/32)          // 3136 conv blocks
#define NB8  (NBLK/8)               // 392 blocks per XCD span

typedef __attribute__((ext_vector_type(8))) short bf16x8;
typedef __attribute__((ext_vector_type(4))) short s16x4;
typedef __attribute__((ext_vector_type(4))) float f32x4;

__device__ inline short f2bf(float f) {
    unsigned u = __float_as_uint(f);
    u += 0x7FFF + ((u >> 16) & 1);
    return (short)(u >> 16);
}
__device__ inline float bf2f(short h) {
    return __uint_as_float(((unsigned)(unsigned short)h) << 16);
}
__device__ inline void split_bf(float x, short& hi, short& lo) {
    hi = f2bf(x);
    lo = f2bf(x - bf2f(hi));
}
__device__ inline void split_bf4(float a, float b, float c, float d,
                                 s16x4& h4, s16x4& l4) {
    short h0, l0, h1, l1, h2, l2, h3, l3;
    split_bf(a, h0, l0); split_bf(b, h1, l1);
    split_bf(c, h2, l2); split_bf(d, h3, l3);
    h4 = (s16x4){h0, h1, h2, h3};
    l4 = (s16x4){l0, l1, l2, l3};
}
// XCD-aware swizzle: consecutive blocks on one XCD (blockIdx%8 assumed XCD id)
// cover one contiguous pixel span -> per-XCD L2 working set ~4 MB.
__device__ inline int swizzle_blk(int raw) {
    return (raw & 7) * NB8 + (raw >> 3);
}

// ---------------------------------------------------------------------------
// Weight prep: split into hi/lo bf16 AND permute K from c*9+tap to
// chunk*288 + tap*32 + cc  (so sampled NHWC channel runs are contiguous in k).
// ---------------------------------------------------------------------------
__global__ __launch_bounds__(256) void k_prepw(const float* __restrict__ wconv,
                                               const float* __restrict__ woff,
                                               short* __restrict__ Wtdh,
                                               short* __restrict__ Wtdl,
                                               short* __restrict__ Wtoh,
                                               short* __restrict__ Wtol) {
    int t = blockIdx.x * 256 + threadIdx.x;
    if (t < COUT * K576) {
        int n = t / K576, kp = t - n * K576;
        int chunk = kp / KCHUNK, r = kp - chunk * KCHUNK;
        int tap = r >> 5, cc = r & 31;
        int c = chunk * 32 + cc;
        short h, l; split_bf(wconv[n * K576 + c * 9 + tap], h, l);
        Wtdh[t] = h; Wtdl[t] = l;
    }
    int t2 = t - COUT * K576;
    if (t2 >= 0 && t2 < 32 * K576) {
        int n = t2 / K576, kp = t2 - n * K576;
        int chunk = kp / KCHUNK, r = kp - chunk * KCHUNK;
        int tap = r >> 5, cc = r & 31;
        int c = chunk * 32 + cc;
        float v = (n < NOFF) ? woff[n * K576 + c * 9 + tap] : 0.0f;
        short h, l; split_bf(v, h, l);
        Wtoh[t2] = h; Wtol[t2] = l;
    }
}

// ---------------------------------------------------------------------------
// x NCHW -> NHWC. Tile 64 px x 64 ch via LDS.  grid = B*HW/64.
// ---------------------------------------------------------------------------
__global__ __launch_bounds__(256) void k_transpose(const float* __restrict__ x,
                                                   float* __restrict__ xT) {
    __shared__ float Lt[64][65];
    int blk = blockIdx.x, t = threadIdx.x;
    int px0 = blk * 64;
    int b   = px0 / HW;
    int ij0 = px0 - b * HW;
    int lane = t & 63, g = t >> 6;
#pragma unroll
    for (int r = 0; r < 16; ++r) {
        int c = r * 4 + g;
        Lt[c][lane] = x[(b * CIN + c) * HW + ij0 + lane];
    }
    __syncthreads();
#pragma unroll
    for (int r = 0; r < 16; ++r) {
        int px = r * 4 + g;
        xT[((size_t)(b * HW + ij0 + px)) * 64 + lane] = Lt[lane][px];
    }
}

// ---------------------------------------------------------------------------
// Offset conv (dense 3x3, pad 1) as split-bf16 MFMA GEMM on NHWC input.
// M=32 px/block, N=32 (18 live), K=576 in 2 chunks. 256 thr = 4 waves.
// ---------------------------------------------------------------------------
__global__ __launch_bounds__(256, 4) void k_offconv(const float* __restrict__ xT,
                                                    const short* __restrict__ Wtoh,
                                                    const short* __restrict__ Wtol,
                                                    const float* __restrict__ boff,
                                                    float* __restrict__ off) {
    __shared__ __align__(16) char smem[2 * 32 * AROW * 2];  // 37888 B
    short* Ah = (short*)smem;
    short* Al = Ah + 32 * AROW;

    const int t    = threadIdx.x;
    const int lane = t & 63;
    const int wave = t >> 6;
    const int px0  = swizzle_blk(blockIdx.x) * 32;   // grid = B*HW/32
    const int b    = px0 / HW;
    const int ij0  = px0 - b * HW;
    const int spx  = t & 31;                   // sampling: pixel
    const int cg   = t >> 5;                   // sampling: 8 groups of 4 ch
    const int ij   = ij0 + spx;
    const int i    = ij / W;
    const int j    = ij - i * W;
    const int l15  = lane & 15;
    const int quad = lane >> 4;
    const int mtb  = wave >> 1;                // compute: m-tile 0..1
    const int ntb  = wave & 1;                 // compute: n-tile 0..1

    const float* xb = xT + (size_t)(b * HW) * 64;

    f32x4 acc = (f32x4){0.f, 0.f, 0.f, 0.f};

    for (int chunk = 0; chunk < 2; ++chunk) {
        const int ch = chunk * 32 + cg * 4;
        short* wrh = &Ah[spx * AROW + cg * 4];
        short* wrl = &Al[spx * AROW + cg * 4];
#pragma unroll
        for (int n = 0; n < 9; ++n) {
            int ii = i + n / 3 - 1, jj = j + n % 3 - 1;
            bool ok = (ii >= 0) & (ii < H) & (jj >= 0) & (jj < W);
            float4 v = make_float4(0.f, 0.f, 0.f, 0.f);
            if (ok) v = *(const float4*)(xb + (size_t)(ii * W + jj) * 64 + ch);
            s16x4 h4, l4;
            split_bf4(v.x, v.y, v.z, v.w, h4, l4);
            *(s16x4*)(wrh + n * 32) = h4;
            *(s16x4*)(wrl + n * 32) = l4;
        }
        __syncthreads();
        const short* aph = &Ah[(mtb * 16 + l15) * AROW + quad * 8];
        const short* apl = &Al[(mtb * 16 + l15) * AROW + quad * 8];
        const short* bph = Wtoh + (ntb * 16 + l15) * K576 + chunk * KCHUNK + quad * 8;
        const short* bpl = Wtol + (ntb * 16 + l15) * K576 + chunk * KCHUNK + quad * 8;
#pragma unroll
        for (int kt = 0; kt < 9; ++kt) {
            bf16x8 afh = *(const bf16x8*)(aph + kt * 32);
            bf16x8 afl = *(const bf16x8*)(apl + kt * 32);
            bf16x8 bfh = *(const bf16x8*)(bph + kt * 32);
            bf16x8 bfl = *(const bf16x8*)(bpl + kt * 32);
            acc = __builtin_amdgcn_mfma_f32_16x16x32_bf16(afh, bfh, acc, 0, 0, 0);
            acc = __builtin_amdgcn_mfma_f32_16x16x32_bf16(afl, bfh, acc, 0, 0, 0);
            acc = __builtin_amdgcn_mfma_f32_16x16x32_bf16(afh, bfl, acc, 0, 0, 0);
        }
        __syncthreads();
    }

    // Repack: Ld[px][20] then full-line-ish stores.
    float* Ld = (float*)smem;
    int n = ntb * 16 + l15;                    // 0..31
    if (n < OFFS) {
        float bi = (n < NOFF) ? boff[n] : 0.0f;
        int pxr = mtb * 16 + quad * 4;
#pragma unroll
        for (int r = 0; r < 4; ++r)
            Ld[(pxr + r) * OFFS + n] = acc[r] + bi;
    }
    __syncthreads();
    {
        int px = t >> 3, c4 = t & 7;
        if (c4 < 5) {
            float4 v = *(float4*)&Ld[px * OFFS + c4 * 4];
            *(float4*)(off + (size_t)(b * HW + ij0 + px) * OFFS + c4 * 4) = v;
        }
    }
}

// ---------------------------------------------------------------------------
// Deformable sampling + conv as split-bf16 MFMA GEMM on NHWC input.
// M=32 px, N=64, K=576 (2 chunks). OUT_NHWC: stage-1 NHWC; else NCHW.
// ---------------------------------------------------------------------------
template <bool OUT_NHWC>
__global__ __launch_bounds__(256, 4) void k_deform(const float* __restrict__ xT,
                                                   const float* __restrict__ off,
                                                   const short* __restrict__ Wtdh,
                                                   const short* __restrict__ Wtdl,
                                                   float* __restrict__ out) {
    __shared__ __align__(16) char smem[2 * 32 * AROW * 2];  // 37888 B
    short* Ah = (short*)smem;
    short* Al = Ah + 32 * AROW;

    const int t    = threadIdx.x;
    const int lane = t & 63;
    const int wave = t >> 6;
    const int px0  = swizzle_blk(blockIdx.x) * 32;   // grid = B*HW/32
    const int b    = px0 / HW;
    const int ij0  = px0 - b * HW;
    const int spx  = t & 31;
    const int cg   = t >> 5;
    const int ij   = ij0 + spx;
    const int i    = ij / W;
    const int j    = ij - i * W;
    const int l15  = lane & 15;
    const int quad = lane >> 4;
    const int mtb  = wave >> 1;                // m-tile 0..1
    const int ntb0 = (wave & 1) * 2;           // n-tiles {0,1} or {2,3}

    const float* xb = xT + (size_t)(b * HW) * 64;

    // load 18 offsets for this pixel (vectorized, stride-20 layout)
    float offa[20];
#pragma unroll
    for (int k = 0; k < 5; ++k)
        *(float4*)&offa[k * 4] = *(const float4*)(off + (size_t)(b * HW + ij) * OFFS + k * 4);

    f32x4 acc[2];
    acc[0] = (f32x4){0.f, 0.f, 0.f, 0.f};
    acc[1] = (f32x4){0.f, 0.f, 0.f, 0.f};

    for (int chunk = 0; chunk < 2; ++chunk) {
        const int ch = chunk * 32 + cg * 4;
        short* wrh = &Ah[spx * AROW + cg * 4];
        short* wrl = &Al[spx * AROW + cg * 4];
#pragma unroll
        for (int n = 0; n < 9; ++n) {
            float px_f = (float)(i + n / 3) + offa[n];
            float py_f = (float)(j + n % 3) + offa[9 + n];
            float qx = floorf(px_f), qy = floorf(py_f);
            int ltx = min(max((int)qx, 0), H - 1);
            int lty = min(max((int)qy, 0), W - 1);
            int rbx = min(max((int)qx + 1, 0), H - 1);
            int rby = min(max((int)qy + 1, 0), W - 1);
            float px = fminf(fmaxf(px_f, 0.0f), (float)(H - 1));
            float py = fminf(fmaxf(py_f, 0.0f), (float)(W - 1));
            float alt = 1.0f + ((float)ltx - px);
            float arb = 1.0f - ((float)rbx - px);
            float blt = 1.0f + ((float)lty - py);
            float brb = 1.0f - ((float)rby - py);
            float g0 = alt * blt, g1 = arb * brb, g2 = alt * brb, g3 = arb * blt;
            const float4 v0 = *(const float4*)(xb + (size_t)(ltx * W + lty) * 64 + ch);
            const float4 v1 = *(const float4*)(xb + (size_t)(rbx * W + rby) * 64 + ch);
            const float4 v2 = *(const float4*)(xb + (size_t)(ltx * W + rby) * 64 + ch);
            const float4 v3 = *(const float4*)(xb + (size_t)(rbx * W + lty) * 64 + ch);
            float s0 = g0 * v0.x + g1 * v1.x + g2 * v2.x + g3 * v3.x;
            float s1 = g0 * v0.y + g1 * v1.y + g2 * v2.y + g3 * v3.y;
            float s2 = g0 * v0.z + g1 * v1.z + g2 * v2.z + g3 * v3.z;
            float s3 = g0 * v0.w + g1 * v1.w + g2 * v2.w + g3 * v3.w;
            s16x4 h4, l4;
            split_bf4(s0, s1, s2, s3, h4, l4);
            *(s16x4*)(wrh + n * 32) = h4;
            *(s16x4*)(wrl + n * 32) = l4;
        }
        __syncthreads();
        const short* aph = &Ah[(mtb * 16 + l15) * AROW + quad * 8];
        const short* apl = &Al[(mtb * 16 + l15) * AROW + quad * 8];
        const short* bh0 = Wtdh + (ntb0 * 16 + l15) * K576 + chunk * KCHUNK + quad * 8;
        const short* bl0 = Wtdl + (ntb0 * 16 + l15) * K576 + chunk * KCHUNK + quad * 8;
#pragma unroll
        for (int kt = 0; kt < 9; ++kt) {
            bf16x8 afh = *(const bf16x8*)(aph + kt * 32);
            bf16x8 afl = *(const bf16x8*)(apl + kt * 32);
#pragma unroll
            for (int nt = 0; nt < 2; ++nt) {
                bf16x8 bfh = *(const bf16x8*)(bh0 + nt * 16 * K576 + kt * 32);
                bf16x8 bfl = *(const bf16x8*)(bl0 + nt * 16 * K576 + kt * 32);
                acc[nt] = __builtin_amdgcn_mfma_f32_16x16x32_bf16(afh, bfh, acc[nt], 0, 0, 0);
                acc[nt] = __builtin_amdgcn_mfma_f32_16x16x32_bf16(afl, bfh, acc[nt], 0, 0, 0);
                acc[nt] = __builtin_amdgcn_mfma_f32_16x16x32_bf16(afh, bfl, acc[nt], 0, 0, 0);
            }
        }
        __syncthreads();
    }

    float* Ld = (float*)smem;
    if (OUT_NHWC) {
        // Ld[px][72]: px-major, channel-contiguous reads
        int pxr = mtb * 16 + quad * 4;
#pragma unroll
        for (int nt = 0; nt < 2; ++nt) {
            int c = (ntb0 + nt) * 16 + l15;
#pragma unroll
            for (int r = 0; r < 4; ++r)
                Ld[(pxr + r) * 72 + c] = acc[nt][r];
        }
        __syncthreads();
#pragma unroll
        for (int r = 0; r < 2; ++r) {
            int px = (t >> 4) + r * 16, c4 = t & 15;
            float4 v = *(float4*)&Ld[px * 72 + c4 * 4];
            *(float4*)(out + (size_t)(b * HW + ij0 + px) * 64 + c4 * 4) = v;
        }
    } else {
        // Ld[c][36]: channel-major, pixel-contiguous reads -> full NCHW lines
        int pxr = mtb * 16 + quad * 4;
#pragma unroll
        for (int nt = 0; nt < 2; ++nt) {
            int c = (ntb0 + nt) * 16 + l15;
#pragma unroll
            for (int r = 0; r < 4; ++r)
                Ld[c * 36 + pxr + r] = acc[nt][r];
        }
        __syncthreads();
#pragma unroll
        for (int cc = 0; cc < 2; ++cc) {
            int c = cc * 32 + (t >> 3), p4 = t & 7;
            float4 v = *(float4*)&Ld[c * 36 + p4 * 4];
            *(float4*)(out + (size_t)(b * COUT + c) * HW + ij0 + p4 * 4) = v;
        }
    }
}

// ---------------------------------------------------------------------------
// Stats on NHWC: grid 196 blocks x 512 px. part[c*256+blk]=sum,
// part[16384 + c*256+blk]=sumsq.
// ---------------------------------------------------------------------------
__global__ __launch_bounds__(256) void k_stats_nhwc(const float* __restrict__ y,
                                                    float* __restrict__ part) {
    __shared__ float Ls[16 * 64], Lq[16 * 64];
    int t = threadIdx.x, blk = blockIdx.x;
    int c4 = (t & 15) * 4, sub = t >> 4;
    float4 s4 = make_float4(0.f, 0.f, 0.f, 0.f), q4 = s4;
    const float* p = y + ((size_t)blk * 512 + sub * 32) * 64 + c4;
    for (int k = 0; k < 32; ++k) {
        float4 v = *(const float4*)(p + (size_t)k * 64);
        s4.x += v.x; s4.y += v.y; s4.z += v.z; s4.w += v.w;
        q4.x += v.x * v.x; q4.y += v.y * v.y; q4.z += v.z * v.z; q4.w += v.w * v.w;
    }
    *(float4*)&Ls[sub * 64 + c4] = s4;
    *(float4*)&Lq[sub * 64 + c4] = q4;
    __syncthreads();
    if (t < 64) {
        float s = 0.f, q = 0.f;
#pragma unroll
        for (int k = 0; k < 16; ++k) { s += Ls[k * 64 + t]; q += Lq[k * 64 + t]; }
        part[t * 256 + blk]         = s;
        part[16384 + t * 256 + blk] = q;
    }
}

// ---------------------------------------------------------------------------
// Stats on NCHW: grid = 64 ch x 7 segs (HW = 7 * 7168).
// ---------------------------------------------------------------------------
__global__ __launch_bounds__(256) void k_stats_nchw(const float* __restrict__ y,
                                                    float* __restrict__ part) {
    int c = blockIdx.x / 7, s = blockIdx.x % 7;
    int t = threadIdx.x;
    float4 s4 = make_float4(0.f, 0.f, 0.f, 0.f), q4 = s4;
    for (int b = 0; b < BATCH; ++b) {
        const float* p = y + (size_t)(b * COUT + c) * HW + s * 7168 + t * 4;
        for (int k = 0; k < 7; ++k) {
            float4 v = *(const float4*)(p + k * 1024);
            s4.x += v.x; s4.y += v.y; s4.z += v.z; s4.w += v.w;
            q4.x += v.x * v.x; q4.y += v.y * v.y; q4.z += v.z * v.z; q4.w += v.w * v.w;
        }
    }
    float sum = s4.x + s4.y + s4.z + s4.w;
    float sq  = q4.x + q4.y + q4.z + q4.w;
#pragma unroll
    for (int d = 32; d > 0; d >>= 1) {
        sum += __shfl_down(sum, d, 64);
        sq  += __shfl_down(sq,  d, 64);
    }
    __shared__ float red[8];
    int wv = t >> 6;
    if ((t & 63) == 0) { red[wv] = sum; red[4 + wv] = sq; }
    __syncthreads();
    if (t == 0) {
        part[c * 256 + s]         = red[0] + red[1] + red[2] + red[3];
        part[16384 + c * 256 + s] = red[4] + red[5] + red[6] + red[7];
    }
}

// ---------------------------------------------------------------------------
// Combine partials -> per-channel scale/shift.  ss[c]=scale, ss[64+c]=shift.
// ---------------------------------------------------------------------------
__global__ __launch_bounds__(256) void k_stats2(const float* __restrict__ part,
                                                int nseg,
                                                const float* __restrict__ gamma,
                                                const float* __restrict__ beta,
                                                float* __restrict__ ss) {
    __shared__ float R[2][4][64];
    int t = threadIdx.x, c = t & 63, g = t >> 6;
    float s = 0.f, q = 0.f;
    for (int k = g; k < nseg; k += 4) {
        s += part[c * 256 + k];
        q += part[16384 + c * 256 + k];
    }
    R[0][g][c] = s; R[1][g][c] = q;
    __syncthreads();
    if (t < 64) {
        float ts = R[0][0][t] + R[0][1][t] + R[0][2][t] + R[0][3][t];
        float tq = R[1][0][t] + R[1][1][t] + R[1][2][t] + R[1][3][t];
        const float inv_m = 1.0f / (float)(BATCH * HW);
        float mu    = ts * inv_m;
        float var   = tq * inv_m - mu * mu;
        float scale = rsqrtf(var + 1e-5f) * gamma[t];
        ss[t]      = scale;
        ss[64 + t] = beta[t] - mu * scale;
    }
}

// ---------------------------------------------------------------------------
// BN+ReLU on NHWC (stage 1): y (NHWC) -> out (NHWC). f4, grid = B*HW*64/1024.
// ---------------------------------------------------------------------------
__global__ __launch_bounds__(256) void k_bnrelu_nhwc(const float* __restrict__ y,
                                                     const float* __restrict__ ss,
                                                     float* __restrict__ out) {
    size_t idx = ((size_t)blockIdx.x * 256 + threadIdx.x) * 4;
    int c4 = (int)(idx & 63);
    float4 sc = *(const float4*)(ss + c4);
    float4 sh = *(const float4*)(ss + 64 + c4);
    float4 v  = *(const float4*)(y + idx);
    float4 r;
    r.x = fmaxf(fmaf(v.x, sc.x, sh.x), 0.f);
    r.y = fmaxf(fmaf(v.y, sc.y, sh.y), 0.f);
    r.z = fmaxf(fmaf(v.z, sc.z, sh.z), 0.f);
    r.w = fmaxf(fmaf(v.w, sc.w, sh.w), 0.f);
    *(float4*)(out + idx) = r;
}

// ---------------------------------------------------------------------------
// BN+ReLU on NCHW, IN-PLACE (stage 2). Each block = 1024 elems in one channel
// (HW = 49*1024). grid = B*64*49.
// ---------------------------------------------------------------------------
__global__ __launch_bounds__(256) void k_bnrelu_nchw(float* __restrict__ y,
                                                     const float* __restrict__ ss) {
    int c = (blockIdx.x / 49) % COUT;      // block-uniform
    float scale = ss[c], shift = ss[64 + c];
    size_t idx = ((size_t)blockIdx.x * 1024) + threadIdx.x * 4;
    float4 v = *(const float4*)(y + idx);
    float4 r;
    r.x = fmaxf(fmaf(v.x, scale, shift), 0.f);
    r.y = fmaxf(fmaf(v.y, scale, shift), 0.f);
    r.z = fmaxf(fmaf(v.z, scale, shift), 0.f);
    r.w = fmaxf(fmaf(v.w, scale, shift), 0.f);
    *(float4*)(y + idx) = r;
}

// ---------------------------------------------------------------------------
// Workspace (34.1 MB): weights 216 KB | part 128 KB | ss 512 B |
// bufC(off20) 8.0 MB | bufB(xT / y1 NHWC) 25.7 MB.
// d_out triple-duty: yraw1 (NHWC) -> yraw2 (NCHW) -> final (in-place BN).
// ---------------------------------------------------------------------------
extern "C" void kernel_launch(void* const* d_in, const int* in_sizes, int n_in,
                              void* d_out, int out_size, void* d_ws, size_t ws_size,
                              hipStream_t stream) {
    const float* x       = (const float*)d_in[0];
    const float* w_off1  = (const float*)d_in[1];
    const float* b_off1  = (const float*)d_in[2];
    const float* w_conv1 = (const float*)d_in[3];
    const float* gamma1  = (const float*)d_in[4];
    const float* beta1   = (const float*)d_in[5];
    const float* w_off2  = (const float*)d_in[6];
    const float* b_off2  = (const float*)d_in[7];
    const float* w_conv2 = (const float*)d_in[8];
    const float* gamma2  = (const float*)d_in[9];
    const float* beta2   = (const float*)d_in[10];
    float* out = (float*)d_out;

    char*  wsb  = (char*)d_ws;
    short* Wtdh = (short*)wsb;                           // 73728
    short* Wtdl = (short*)(wsb + 73728);                 // 73728
    short* Wtoh = (short*)(wsb + 147456);                // 36864
    short* Wtol = (short*)(wsb + 184320);                // 36864
    float* part = (float*)(wsb + 221184);                // 131072
    float* ss   = (float*)(wsb + 352256);                // 512
    float* bufC = (float*)(wsb + 352768);                // off20: 8028160
    float* bufB = (float*)(wsb + 8380928);               // xT/y1: 25690112

    const int tp_blocks   = (BATCH * HW) / 64;           // 1568
    const int bn_blocks   = (BATCH * COUT * HW) / 1024;  // 6272

    // ---- stage 1 ----
    k_prepw      <<<216, 256, 0, stream>>>(w_conv1, w_off1, Wtdh, Wtdl, Wtoh, Wtol);
    k_transpose  <<<tp_blocks, 256, 0, stream>>>(x, bufB);
    k_offconv    <<<NBLK, 256, 0, stream>>>(bufB, Wtoh, Wtol, b_off1, bufC);
    k_deform<true><<<NBLK, 256, 0, stream>>>(bufB, bufC, Wtdh, Wtdl, out);
    k_stats_nhwc <<<196, 256, 0, stream>>>(out, part);
    k_stats2     <<<1, 256, 0, stream>>>(part, 196, gamma1, beta1, ss);
    k_bnrelu_nhwc<<<bn_blocks, 256, 0, stream>>>(out, ss, bufB);   // y1 (NHWC)

    // ---- stage 2 ----
    k_prepw      <<<216, 256, 0, stream>>>(w_conv2, w_off2, Wtdh, Wtdl, Wtoh, Wtol);
    k_offconv    <<<NBLK, 256, 0, stream>>>(bufB, Wtoh, Wtol, b_off2, bufC);
    k_deform<false><<<NBLK, 256, 0, stream>>>(bufB, bufC, Wtdh, Wtdl, out);
    k_stats_nchw <<<448, 256, 0, stream>>>(out, part);
    k_stats2     <<<1, 256, 0, stream>>>(part, 7, gamma2, beta2, ss);
    k_bnrelu_nchw<<<bn_blocks, 256, 0, stream>>>(out, ss);         // in-place
}

// Round 9
// 681.345 us; speedup vs baseline: 2.8671x; 1.2408x over previous
//
#include <hip/hip_runtime.h>

#define H 224
#define W 224
#define HW (H*W)
#define BATCH 2
#define CIN 64
#define COUT 64
#define NOFF 18
#define K576 576          // K = 64 ch * 9 taps
#define KCHUNK 288        // 32 ch * 9 taps per chunk (k = tap*32 + cc)
#define AROW 296          // 288 + 8 bf16 pad (592 B rows, 16B-aligned)
#define OFFS 20           // off stored NHWC with stride 20 (18 live, f4-aligned)
#define NBLK (BATCH*HW/32)          // 3136 conv blocks (4x8-pixel tiles)
#define NB8  (NBLK/8)               // 392 blocks per XCD span
#define TROW 56                     // row-tiles (224/4)
#define TCOL 28                     // col-tiles (224/8)
#define SROW 36                     // staged-patch stride in floats (144 B, 16B-aligned, bank-spread)

typedef __attribute__((ext_vector_type(8))) short bf16x8;
typedef __attribute__((ext_vector_type(4))) short s16x4;
typedef __attribute__((ext_vector_type(4))) float f32x4;

__device__ inline short f2bf(float f) {
    unsigned u = __float_as_uint(f);
    u += 0x7FFF + ((u >> 16) & 1);
    return (short)(u >> 16);
}
__device__ inline float bf2f(short h) {
    return __uint_as_float(((unsigned)(unsigned short)h) << 16);
}
__device__ inline void split_bf(float x, short& hi, short& lo) {
    hi = f2bf(x);
    lo = f2bf(x - bf2f(hi));
}
__device__ inline void split_bf4(float a, float b, float c, float d,
                                 s16x4& h4, s16x4& l4) {
    short h0, l0, h1, l1, h2, l2, h3, l3;
    split_bf(a, h0, l0); split_bf(b, h1, l1);
    split_bf(c, h2, l2); split_bf(d, h3, l3);
    h4 = (s16x4){h0, h1, h2, h3};
    l4 = (s16x4){l0, l1, l2, l3};
}
// XCD-aware swizzle: consecutive virtual blocks per XCD cover contiguous tile rows.
__device__ inline int swizzle_blk(int raw) {
    return (raw & 7) * NB8 + (raw >> 3);
}

// ---------------------------------------------------------------------------
// Weight prep: split into hi/lo bf16 AND permute K from c*9+tap to
// chunk*288 + tap*32 + cc.
// ---------------------------------------------------------------------------
__global__ __launch_bounds__(256) void k_prepw(const float* __restrict__ wconv,
                                               const float* __restrict__ woff,
                                               short* __restrict__ Wtdh,
                                               short* __restrict__ Wtdl,
                                               short* __restrict__ Wtoh,
                                               short* __restrict__ Wtol) {
    int t = blockIdx.x * 256 + threadIdx.x;
    if (t < COUT * K576) {
        int n = t / K576, kp = t - n * K576;
        int chunk = kp / KCHUNK, r = kp - chunk * KCHUNK;
        int tap = r >> 5, cc = r & 31;
        int c = chunk * 32 + cc;
        short h, l; split_bf(wconv[n * K576 + c * 9 + tap], h, l);
        Wtdh[t] = h; Wtdl[t] = l;
    }
    int t2 = t - COUT * K576;
    if (t2 >= 0 && t2 < 32 * K576) {
        int n = t2 / K576, kp = t2 - n * K576;
        int chunk = kp / KCHUNK, r = kp - chunk * KCHUNK;
        int tap = r >> 5, cc = r & 31;
        int c = chunk * 32 + cc;
        float v = (n < NOFF) ? woff[n * K576 + c * 9 + tap] : 0.0f;
        short h, l; split_bf(v, h, l);
        Wtoh[t2] = h; Wtol[t2] = l;
    }
}

// ---------------------------------------------------------------------------
// x NCHW -> NHWC. Tile 64 px x 64 ch via LDS.  grid = B*HW/64.
// ---------------------------------------------------------------------------
__global__ __launch_bounds__(256) void k_transpose(const float* __restrict__ x,
                                                   float* __restrict__ xT) {
    __shared__ float Lt[64][65];
    int blk = blockIdx.x, t = threadIdx.x;
    int px0 = blk * 64;
    int b   = px0 / HW;
    int ij0 = px0 - b * HW;
    int lane = t & 63, g = t >> 6;
#pragma unroll
    for (int r = 0; r < 16; ++r) {
        int c = r * 4 + g;
        Lt[c][lane] = x[(b * CIN + c) * HW + ij0 + lane];
    }
    __syncthreads();
#pragma unroll
    for (int r = 0; r < 16; ++r) {
        int px = r * 4 + g;
        xT[((size_t)(b * HW + ij0 + px)) * 64 + lane] = Lt[lane][px];
    }
}

// ---------------------------------------------------------------------------
// Offset conv (dense 3x3, pad 1) as split-bf16 MFMA GEMM on NHWC input.
// 4x8 pixel tile; 6x10x32ch patch staged in LDS (zero-padded) -> all tap
// reads are LDS. M=32, N=32 (18 live), K=576 in 2 chunks. 256 thr = 4 waves.
// ---------------------------------------------------------------------------
__global__ __launch_bounds__(256, 3) void k_offconv(const float* __restrict__ xT,
                                                    const short* __restrict__ Wtoh,
                                                    const short* __restrict__ Wtol,
                                                    const float* __restrict__ boff,
                                                    float* __restrict__ off) {
    __shared__ __align__(16) char smem[2 * 32 * AROW * 2 + 60 * SROW * 4]; // 46528 B
    short* Ah = (short*)smem;
    short* Al = Ah + 32 * AROW;
    float* Xs = (float*)(smem + 2 * 32 * AROW * 2);   // 60 slots x 36 floats

    const int t    = threadIdx.x;
    const int lane = t & 63;
    const int wave = t >> 6;
    const int vb   = swizzle_blk(blockIdx.x);
    const int b    = vb / (TROW * TCOL);
    const int rem  = vb - b * (TROW * TCOL);
    const int i0   = (rem / TCOL) * 4;
    const int j0   = (rem % TCOL) * 8;
    const int spx  = t & 31;
    const int cg   = t >> 5;
    const int pr   = spx >> 3, pc = spx & 7;
    const int l15  = lane & 15;
    const int quad = lane >> 4;
    const int mtb  = wave >> 1;
    const int ntb  = wave & 1;

    const float* xb = xT + (size_t)(b * HW) * 64;

    f32x4 acc = (f32x4){0.f, 0.f, 0.f, 0.f};

    for (int chunk = 0; chunk < 2; ++chunk) {
        // ---- stage 6x10 patch (zero-padded outside image) ----
#pragma unroll
        for (int k = 0; k < 2; ++k) {
            int idx = k * 256 + t;
            if (idx < 480) {
                int slot = idx >> 3, e = idx & 7;
                int sr = slot / 10, sc = slot - sr * 10;
                int rr = i0 - 1 + sr, cc = j0 - 1 + sc;
                bool ok = (rr >= 0) & (rr < H) & (cc >= 0) & (cc < W);
                float4 v = make_float4(0.f, 0.f, 0.f, 0.f);
                if (ok) v = *(const float4*)(xb + (size_t)(rr * W + cc) * 64 + chunk * 32 + e * 4);
                *(float4*)&Xs[slot * SROW + e * 4] = v;
            }
        }
        __syncthreads();
        // ---- sample from LDS -> A-tile ----
        short* wrh = &Ah[spx * AROW + cg * 4];
        short* wrl = &Al[spx * AROW + cg * 4];
#pragma unroll
        for (int n = 0; n < 9; ++n) {
            int slot = (pr + n / 3) * 10 + (pc + n % 3);
            float4 v = *(float4*)&Xs[slot * SROW + cg * 4];
            s16x4 h4, l4;
            split_bf4(v.x, v.y, v.z, v.w, h4, l4);
            *(s16x4*)(wrh + n * 32) = h4;
            *(s16x4*)(wrl + n * 32) = l4;
        }
        __syncthreads();
        const short* aph = &Ah[(mtb * 16 + l15) * AROW + quad * 8];
        const short* apl = &Al[(mtb * 16 + l15) * AROW + quad * 8];
        const short* bph = Wtoh + (ntb * 16 + l15) * K576 + chunk * KCHUNK + quad * 8;
        const short* bpl = Wtol + (ntb * 16 + l15) * K576 + chunk * KCHUNK + quad * 8;
#pragma unroll
        for (int kt = 0; kt < 9; ++kt) {
            bf16x8 afh = *(const bf16x8*)(aph + kt * 32);
            bf16x8 afl = *(const bf16x8*)(apl + kt * 32);
            bf16x8 bfh = *(const bf16x8*)(bph + kt * 32);
            bf16x8 bfl = *(const bf16x8*)(bpl + kt * 32);
            acc = __builtin_amdgcn_mfma_f32_16x16x32_bf16(afh, bfh, acc, 0, 0, 0);
            acc = __builtin_amdgcn_mfma_f32_16x16x32_bf16(afl, bfh, acc, 0, 0, 0);
            acc = __builtin_amdgcn_mfma_f32_16x16x32_bf16(afh, bfl, acc, 0, 0, 0);
        }
        __syncthreads();
    }

    // Repack: Ld[px][20] then 320-B-run stores (4-px tile rows).
    float* Ld = (float*)smem;
    int n = ntb * 16 + l15;
    if (n < OFFS) {
        float bi = (n < NOFF) ? boff[n] : 0.0f;
        int pxr = mtb * 16 + quad * 4;
#pragma unroll
        for (int r = 0; r < 4; ++r)
            Ld[(pxr + r) * OFFS + n] = acc[r] + bi;
    }
    __syncthreads();
    {
        int px = t >> 3, c4 = t & 7;
        if (c4 < 5) {
            float4 v = *(float4*)&Ld[px * OFFS + c4 * 4];
            int ij = (i0 + (px >> 3)) * W + j0 + (px & 7);
            *(float4*)(off + (size_t)(b * HW + ij) * OFFS + c4 * 4) = v;
        }
    }
}

// ---------------------------------------------------------------------------
// Deformable sampling + conv as split-bf16 MFMA GEMM on NHWC input.
// 4x8 pixel tile; 8x12x32ch patch staged in LDS (border-replicated) covers
// all corners for |off|<1; rare out-of-patch taps fall back to global loads.
// M=32, N=64, K=576 (2 chunks). OUT_NHWC: stage-1 NHWC; else NCHW.
// ---------------------------------------------------------------------------
template <bool OUT_NHWC>
__global__ __launch_bounds__(256, 3) void k_deform(const float* __restrict__ xT,
                                                   const float* __restrict__ off,
                                                   const short* __restrict__ Wtdh,
                                                   const short* __restrict__ Wtdl,
                                                   float* __restrict__ out) {
    __shared__ __align__(16) char smem[2 * 32 * AROW * 2 + 96 * SROW * 4]; // 51712 B
    short* Ah = (short*)smem;
    short* Al = Ah + 32 * AROW;
    float* Xs = (float*)(smem + 2 * 32 * AROW * 2);   // 96 slots x 36 floats

    const int t    = threadIdx.x;
    const int lane = t & 63;
    const int wave = t >> 6;
    const int vb   = swizzle_blk(blockIdx.x);
    const int b    = vb / (TROW * TCOL);
    const int rem  = vb - b * (TROW * TCOL);
    const int i0   = (rem / TCOL) * 4;
    const int j0   = (rem % TCOL) * 8;
    const int spx  = t & 31;
    const int cg   = t >> 5;
    const int pr   = spx >> 3, pc = spx & 7;
    const int i    = i0 + pr, j = j0 + pc;
    const int ij   = i * W + j;
    const int l15  = lane & 15;
    const int quad = lane >> 4;
    const int mtb  = wave >> 1;
    const int ntb0 = (wave & 1) * 2;

    const float* xb = xT + (size_t)(b * HW) * 64;

    float offa[20];
#pragma unroll
    for (int k = 0; k < 5; ++k)
        *(float4*)&offa[k * 4] = *(const float4*)(off + (size_t)(b * HW + ij) * OFFS + k * 4);

    f32x4 acc[2];
    acc[0] = (f32x4){0.f, 0.f, 0.f, 0.f};
    acc[1] = (f32x4){0.f, 0.f, 0.f, 0.f};

    for (int chunk = 0; chunk < 2; ++chunk) {
        const int ch = chunk * 32 + cg * 4;
        // ---- stage 8x12 patch, border rows/cols replicated (clamped) ----
#pragma unroll
        for (int k = 0; k < 3; ++k) {
            int idx = k * 256 + t;                 // 768 = 96 slots x 8 f4
            int slot = idx >> 3, e = idx & 7;
            int sr = slot / 12, sc = slot - sr * 12;
            int rr = min(max(i0 - 1 + sr, 0), H - 1);
            int cc = min(max(j0 - 1 + sc, 0), W - 1);
            float4 v = *(const float4*)(xb + (size_t)(rr * W + cc) * 64 + chunk * 32 + e * 4);
            *(float4*)&Xs[slot * SROW + e * 4] = v;
        }
        __syncthreads();
        // ---- sample (LDS fast path, global fallback) -> A-tile ----
        short* wrh = &Ah[spx * AROW + cg * 4];
        short* wrl = &Al[spx * AROW + cg * 4];
#pragma unroll
        for (int n = 0; n < 9; ++n) {
            float px_f = (float)(i + n / 3) + offa[n];
            float py_f = (float)(j + n % 3) + offa[9 + n];
            float qx = floorf(px_f), qy = floorf(py_f);
            int ltx = min(max((int)qx, 0), H - 1);
            int lty = min(max((int)qy, 0), W - 1);
            int rbx = min(max((int)qx + 1, 0), H - 1);
            int rby = min(max((int)qy + 1, 0), W - 1);
            float px = fminf(fmaxf(px_f, 0.0f), (float)(H - 1));
            float py = fminf(fmaxf(py_f, 0.0f), (float)(W - 1));
            float alt = 1.0f + ((float)ltx - px);
            float arb = 1.0f - ((float)rbx - px);
            float blt = 1.0f + ((float)lty - py);
            float brb = 1.0f - ((float)rby - py);
            float g0 = alt * blt, g1 = arb * brb, g2 = alt * brb, g3 = arb * blt;
            int slr = ltx - (i0 - 1), srr = rbx - (i0 - 1);
            int slc = lty - (j0 - 1), src = rby - (j0 - 1);
            float4 v0, v1, v2, v3;
            if (((unsigned)slr < 8u) & ((unsigned)srr < 8u) &
                ((unsigned)slc < 12u) & ((unsigned)src < 12u)) {
                v0 = *(float4*)&Xs[(slr * 12 + slc) * SROW + cg * 4];
                v1 = *(float4*)&Xs[(srr * 12 + src) * SROW + cg * 4];
                v2 = *(float4*)&Xs[(slr * 12 + src) * SROW + cg * 4];
                v3 = *(float4*)&Xs[(srr * 12 + slc) * SROW + cg * 4];
            } else {                                // rare: |off| >= 1
                v0 = *(const float4*)(xb + (size_t)(ltx * W + lty) * 64 + ch);
                v1 = *(const float4*)(xb + (size_t)(rbx * W + rby) * 64 + ch);
                v2 = *(const float4*)(xb + (size_t)(ltx * W + rby) * 64 + ch);
                v3 = *(const float4*)(xb + (size_t)(rbx * W + lty) * 64 + ch);
            }
            float s0 = g0 * v0.x + g1 * v1.x + g2 * v2.x + g3 * v3.x;
            float s1 = g0 * v0.y + g1 * v1.y + g2 * v2.y + g3 * v3.y;
            float s2 = g0 * v0.z + g1 * v1.z + g2 * v2.z + g3 * v3.z;
            float s3 = g0 * v0.w + g1 * v1.w + g2 * v2.w + g3 * v3.w;
            s16x4 h4, l4;
            split_bf4(s0, s1, s2, s3, h4, l4);
            *(s16x4*)(wrh + n * 32) = h4;
            *(s16x4*)(wrl + n * 32) = l4;
        }
        __syncthreads();
        const short* aph = &Ah[(mtb * 16 + l15) * AROW + quad * 8];
        const short* apl = &Al[(mtb * 16 + l15) * AROW + quad * 8];
        const short* bh0 = Wtdh + (ntb0 * 16 + l15) * K576 + chunk * KCHUNK + quad * 8;
        const short* bl0 = Wtdl + (ntb0 * 16 + l15) * K576 + chunk * KCHUNK + quad * 8;
#pragma unroll
        for (int kt = 0; kt < 9; ++kt) {
            bf16x8 afh = *(const bf16x8*)(aph + kt * 32);
            bf16x8 afl = *(const bf16x8*)(apl + kt * 32);
#pragma unroll
            for (int nt = 0; nt < 2; ++nt) {
                bf16x8 bfh = *(const bf16x8*)(bh0 + nt * 16 * K576 + kt * 32);
                bf16x8 bfl = *(const bf16x8*)(bl0 + nt * 16 * K576 + kt * 32);
                acc[nt] = __builtin_amdgcn_mfma_f32_16x16x32_bf16(afh, bfh, acc[nt], 0, 0, 0);
                acc[nt] = __builtin_amdgcn_mfma_f32_16x16x32_bf16(afl, bfh, acc[nt], 0, 0, 0);
                acc[nt] = __builtin_amdgcn_mfma_f32_16x16x32_bf16(afh, bfl, acc[nt], 0, 0, 0);
            }
        }
        __syncthreads();
    }

    float* Ld = (float*)smem;
    if (OUT_NHWC) {
        int pxr = mtb * 16 + quad * 4;
#pragma unroll
        for (int nt = 0; nt < 2; ++nt) {
            int c = (ntb0 + nt) * 16 + l15;
#pragma unroll
            for (int r = 0; r < 4; ++r)
                Ld[(pxr + r) * 72 + c] = acc[nt][r];
        }
        __syncthreads();
#pragma unroll
        for (int r = 0; r < 2; ++r) {
            int px = (t >> 4) + r * 16, c4 = t & 15;
            float4 v = *(float4*)&Ld[px * 72 + c4 * 4];
            int pij = (i0 + (px >> 3)) * W + j0 + (px & 7);
            *(float4*)(out + (size_t)(b * HW + pij) * 64 + c4 * 4) = v;
        }
    } else {
        int pxr = mtb * 16 + quad * 4;
#pragma unroll
        for (int nt = 0; nt < 2; ++nt) {
            int c = (ntb0 + nt) * 16 + l15;
#pragma unroll
            for (int r = 0; r < 4; ++r)
                Ld[c * 36 + pxr + r] = acc[nt][r];
        }
        __syncthreads();
#pragma unroll
        for (int cc = 0; cc < 2; ++cc) {
            int c = cc * 32 + (t >> 3), p4 = t & 7;
            float4 v = *(float4*)&Ld[c * 36 + p4 * 4];
            int px = p4 * 4;
            int pij = (i0 + (px >> 3)) * W + j0 + (px & 7);
            *(float4*)(out + (size_t)(b * COUT + c) * HW + pij) = v;
        }
    }
}

// ---------------------------------------------------------------------------
// Stats on NHWC: grid 196 blocks x 512 px.
// ---------------------------------------------------------------------------
__global__ __launch_bounds__(256) void k_stats_nhwc(const float* __restrict__ y,
                                                    float* __restrict__ part) {
    __shared__ float Ls[16 * 64], Lq[16 * 64];
    int t = threadIdx.x, blk = blockIdx.x;
    int c4 = (t & 15) * 4, sub = t >> 4;
    float4 s4 = make_float4(0.f, 0.f, 0.f, 0.f), q4 = s4;
    const float* p = y + ((size_t)blk * 512 + sub * 32) * 64 + c4;
    for (int k = 0; k < 32; ++k) {
        float4 v = *(const float4*)(p + (size_t)k * 64);
        s4.x += v.x; s4.y += v.y; s4.z += v.z; s4.w += v.w;
        q4.x += v.x * v.x; q4.y += v.y * v.y; q4.z += v.z * v.z; q4.w += v.w * v.w;
    }
    *(float4*)&Ls[sub * 64 + c4] = s4;
    *(float4*)&Lq[sub * 64 + c4] = q4;
    __syncthreads();
    if (t < 64) {
        float s = 0.f, q = 0.f;
#pragma unroll
        for (int k = 0; k < 16; ++k) { s += Ls[k * 64 + t]; q += Lq[k * 64 + t]; }
        part[t * 256 + blk]         = s;
        part[16384 + t * 256 + blk] = q;
    }
}

// ---------------------------------------------------------------------------
// Stats on NCHW: grid = 64 ch x 7 segs.
// ---------------------------------------------------------------------------
__global__ __launch_bounds__(256) void k_stats_nchw(const float* __restrict__ y,
                                                    float* __restrict__ part) {
    int c = blockIdx.x / 7, s = blockIdx.x % 7;
    int t = threadIdx.x;
    float4 s4 = make_float4(0.f, 0.f, 0.f, 0.f), q4 = s4;
    for (int b = 0; b < BATCH; ++b) {
        const float* p = y + (size_t)(b * COUT + c) * HW + s * 7168 + t * 4;
        for (int k = 0; k < 7; ++k) {
            float4 v = *(const float4*)(p + k * 1024);
            s4.x += v.x; s4.y += v.y; s4.z += v.z; s4.w += v.w;
            q4.x += v.x * v.x; q4.y += v.y * v.y; q4.z += v.z * v.z; q4.w += v.w * v.w;
        }
    }
    float sum = s4.x + s4.y + s4.z + s4.w;
    float sq  = q4.x + q4.y + q4.z + q4.w;
#pragma unroll
    for (int d = 32; d > 0; d >>= 1) {
        sum += __shfl_down(sum, d, 64);
        sq  += __shfl_down(sq,  d, 64);
    }
    __shared__ float red[8];
    int wv = t >> 6;
    if ((t & 63) == 0) { red[wv] = sum; red[4 + wv] = sq; }
    __syncthreads();
    if (t == 0) {
        part[c * 256 + s]         = red[0] + red[1] + red[2] + red[3];
        part[16384 + c * 256 + s] = red[4] + red[5] + red[6] + red[7];
    }
}

// ---------------------------------------------------------------------------
// Combine partials -> per-channel scale/shift.
// ---------------------------------------------------------------------------
__global__ __launch_bounds__(256) void k_stats2(const float* __restrict__ part,
                                                int nseg,
                                                const float* __restrict__ gamma,
                                                const float* __restrict__ beta,
                                                float* __restrict__ ss) {
    __shared__ float R[2][4][64];
    int t = threadIdx.x, c = t & 63, g = t >> 6;
    float s = 0.f, q = 0.f;
    for (int k = g; k < nseg; k += 4) {
        s += part[c * 256 + k];
        q += part[16384 + c * 256 + k];
    }
    R[0][g][c] = s; R[1][g][c] = q;
    __syncthreads();
    if (t < 64) {
        float ts = R[0][0][t] + R[0][1][t] + R[0][2][t] + R[0][3][t];
        float tq = R[1][0][t] + R[1][1][t] + R[1][2][t] + R[1][3][t];
        const float inv_m = 1.0f / (float)(BATCH * HW);
        float mu    = ts * inv_m;
        float var   = tq * inv_m - mu * mu;
        float scale = rsqrtf(var + 1e-5f) * gamma[t];
        ss[t]      = scale;
        ss[64 + t] = beta[t] - mu * scale;
    }
}

// ---------------------------------------------------------------------------
// BN+ReLU on NHWC (stage 1).
// ---------------------------------------------------------------------------
__global__ __launch_bounds__(256) void k_bnrelu_nhwc(const float* __restrict__ y,
                                                     const float* __restrict__ ss,
                                                     float* __restrict__ out) {
    size_t idx = ((size_t)blockIdx.x * 256 + threadIdx.x) * 4;
    int c4 = (int)(idx & 63);
    float4 sc = *(const float4*)(ss + c4);
    float4 sh = *(const float4*)(ss + 64 + c4);
    float4 v  = *(const float4*)(y + idx);
    float4 r;
    r.x = fmaxf(fmaf(v.x, sc.x, sh.x), 0.f);
    r.y = fmaxf(fmaf(v.y, sc.y, sh.y), 0.f);
    r.z = fmaxf(fmaf(v.z, sc.z, sh.z), 0.f);
    r.w = fmaxf(fmaf(v.w, sc.w, sh.w), 0.f);
    *(float4*)(out + idx) = r;
}

// ---------------------------------------------------------------------------
// BN+ReLU on NCHW, IN-PLACE (stage 2).
// ---------------------------------------------------------------------------
__global__ __launch_bounds__(256) void k_bnrelu_nchw(float* __restrict__ y,
                                                     const float* __restrict__ ss) {
    int c = (blockIdx.x / 49) % COUT;
    float scale = ss[c], shift = ss[64 + c];
    size_t idx = ((size_t)blockIdx.x * 1024) + threadIdx.x * 4;
    float4 v = *(const float4*)(y + idx);
    float4 r;
    r.x = fmaxf(fmaf(v.x, scale, shift), 0.f);
    r.y = fmaxf(fmaf(v.y, scale, shift), 0.f);
    r.z = fmaxf(fmaf(v.z, scale, shift), 0.f);
    r.w = fmaxf(fmaf(v.w, scale, shift), 0.f);
    *(float4*)(y + idx) = r;
}

// ---------------------------------------------------------------------------
// Workspace (34.1 MB): weights 216 KB | part 128 KB | ss 512 B |
// bufC(off20) 8.0 MB | bufB(xT / y1 NHWC) 25.7 MB.
// ---------------------------------------------------------------------------
extern "C" void kernel_launch(void* const* d_in, const int* in_sizes, int n_in,
                              void* d_out, int out_size, void* d_ws, size_t ws_size,
                              hipStream_t stream) {
    const float* x       = (const float*)d_in[0];
    const float* w_off1  = (const float*)d_in[1];
    const float* b_off1  = (const float*)d_in[2];
    const float* w_conv1 = (const float*)d_in[3];
    const float* gamma1  = (const float*)d_in[4];
    const float* beta1   = (const float*)d_in[5];
    const float* w_off2  = (const float*)d_in[6];
    const float* b_off2  = (const float*)d_in[7];
    const float* w_conv2 = (const float*)d_in[8];
    const float* gamma2  = (const float*)d_in[9];
    const float* beta2   = (const float*)d_in[10];
    float* out = (float*)d_out;

    char*  wsb  = (char*)d_ws;
    short* Wtdh = (short*)wsb;                           // 73728
    short* Wtdl = (short*)(wsb + 73728);                 // 73728
    short* Wtoh = (short*)(wsb + 147456);                // 36864
    short* Wtol = (short*)(wsb + 184320);                // 36864
    float* part = (float*)(wsb + 221184);                // 131072
    float* ss   = (float*)(wsb + 352256);                // 512
    float* bufC = (float*)(wsb + 352768);                // off20: 8028160
    float* bufB = (float*)(wsb + 8380928);               // xT/y1: 25690112

    const int tp_blocks   = (BATCH * HW) / 64;           // 1568
    const int bn_blocks   = (BATCH * COUT * HW) / 1024;  // 6272

    // ---- stage 1 ----
    k_prepw      <<<216, 256, 0, stream>>>(w_conv1, w_off1, Wtdh, Wtdl, Wtoh, Wtol);
    k_transpose  <<<tp_blocks, 256, 0, stream>>>(x, bufB);
    k_offconv    <<<NBLK, 256, 0, stream>>>(bufB, Wtoh, Wtol, b_off1, bufC);
    k_deform<true><<<NBLK, 256, 0, stream>>>(bufB, bufC, Wtdh, Wtdl, out);
    k_stats_nhwc <<<196, 256, 0, stream>>>(out, part);
    k_stats2     <<<1, 256, 0, stream>>>(part, 196, gamma1, beta1, ss);
    k_bnrelu_nhwc<<<bn_blocks, 256, 0, stream>>>(out, ss, bufB);   // y1 (NHWC)

    // ---- stage 2 ----
    k_prepw      <<<216, 256, 0, stream>>>(w_conv2, w_off2, Wtdh, Wtdl, Wtoh, Wtol);
    k_offconv    <<<NBLK, 256, 0, stream>>>(bufB, Wtoh, Wtol, b_off2, bufC);
    k_deform<false><<<NBLK, 256, 0, stream>>>(bufB, bufC, Wtdh, Wtdl, out);
    k_stats_nchw <<<448, 256, 0, stream>>>(out, part);
    k_stats2     <<<1, 256, 0, stream>>>(part, 7, gamma2, beta2, ss);
    k_bnrelu_nchw<<<bn_blocks, 256, 0, stream>>>(out, ss);         // in-place
}

// Round 10
// 675.461 us; speedup vs baseline: 2.8920x; 1.0087x over previous
//
#include <hip/hip_runtime.h>

#define H 224
#define W 224
#define HW (H*W)
#define BATCH 2
#define CIN 64
#define COUT 64
#define NOFF 18
#define K576 576          // K = 64 ch * 9 taps
#define KCHUNK 288        // 32 ch * 9 taps per chunk (k = tap*32 + cc)
#define AROW 296          // 288 + 8 bf16 pad (592 B rows, 16B-aligned)
#define OFFS 20           // off stored NHWC with stride 20 (18 live, f4-aligned)
#define NBLK (BATCH*HW/32)          // 3136 conv blocks (4x8-pixel tiles)
#define NB8  (NBLK/8)               // 392 blocks per XCD span
#define TROW 56                     // row-tiles (224/4)
#define TCOL 28                     // col-tiles (224/8)
#define SROW 36                     // staged-patch stride in floats
#define PSTRIDE 4096                // part stride per channel (pow2 > 3136)
#define PQOFF (64*PSTRIDE)          // sumsq offset in part

typedef __attribute__((ext_vector_type(8))) short bf16x8;
typedef __attribute__((ext_vector_type(4))) short s16x4;
typedef __attribute__((ext_vector_type(4))) float f32x4;

__device__ inline short f2bf(float f) {
    unsigned u = __float_as_uint(f);
    u += 0x7FFF + ((u >> 16) & 1);
    return (short)(u >> 16);
}
__device__ inline float bf2f(short h) {
    return __uint_as_float(((unsigned)(unsigned short)h) << 16);
}
__device__ inline void split_bf(float x, short& hi, short& lo) {
    hi = f2bf(x);
    lo = f2bf(x - bf2f(hi));
}
__device__ inline void split_bf4(float a, float b, float c, float d,
                                 s16x4& h4, s16x4& l4) {
    short h0, l0, h1, l1, h2, l2, h3, l3;
    split_bf(a, h0, l0); split_bf(b, h1, l1);
    split_bf(c, h2, l2); split_bf(d, h3, l3);
    h4 = (s16x4){h0, h1, h2, h3};
    l4 = (s16x4){l0, l1, l2, l3};
}
__device__ inline int swizzle_blk(int raw) {
    return (raw & 7) * NB8 + (raw >> 3);
}

// ---------------------------------------------------------------------------
// Weight prep: split into hi/lo bf16, permute K to chunk*288 + tap*32 + cc.
// ---------------------------------------------------------------------------
__global__ __launch_bounds__(256) void k_prepw(const float* __restrict__ wconv,
                                               const float* __restrict__ woff,
                                               short* __restrict__ Wtdh,
                                               short* __restrict__ Wtdl,
                                               short* __restrict__ Wtoh,
                                               short* __restrict__ Wtol) {
    int t = blockIdx.x * 256 + threadIdx.x;
    if (t < COUT * K576) {
        int n = t / K576, kp = t - n * K576;
        int chunk = kp / KCHUNK, r = kp - chunk * KCHUNK;
        int tap = r >> 5, cc = r & 31;
        int c = chunk * 32 + cc;
        short h, l; split_bf(wconv[n * K576 + c * 9 + tap], h, l);
        Wtdh[t] = h; Wtdl[t] = l;
    }
    int t2 = t - COUT * K576;
    if (t2 >= 0 && t2 < 32 * K576) {
        int n = t2 / K576, kp = t2 - n * K576;
        int chunk = kp / KCHUNK, r = kp - chunk * KCHUNK;
        int tap = r >> 5, cc = r & 31;
        int c = chunk * 32 + cc;
        float v = (n < NOFF) ? woff[n * K576 + c * 9 + tap] : 0.0f;
        short h, l; split_bf(v, h, l);
        Wtoh[t2] = h; Wtol[t2] = l;
    }
}

// ---------------------------------------------------------------------------
// x NCHW -> NHWC.
// ---------------------------------------------------------------------------
__global__ __launch_bounds__(256) void k_transpose(const float* __restrict__ x,
                                                   float* __restrict__ xT) {
    __shared__ float Lt[64][65];
    int blk = blockIdx.x, t = threadIdx.x;
    int px0 = blk * 64;
    int b   = px0 / HW;
    int ij0 = px0 - b * HW;
    int lane = t & 63, g = t >> 6;
#pragma unroll
    for (int r = 0; r < 16; ++r) {
        int c = r * 4 + g;
        Lt[c][lane] = x[(b * CIN + c) * HW + ij0 + lane];
    }
    __syncthreads();
#pragma unroll
    for (int r = 0; r < 16; ++r) {
        int px = r * 4 + g;
        xT[((size_t)(b * HW + ij0 + px)) * 64 + lane] = Lt[lane][px];
    }
}

// ---------------------------------------------------------------------------
// Offset conv (dense 3x3, pad 1) as split-bf16 MFMA GEMM; 4x8 tile,
// 6x10x32ch zero-padded LDS patch.
// ---------------------------------------------------------------------------
__global__ __launch_bounds__(256, 3) void k_offconv(const float* __restrict__ xT,
                                                    const short* __restrict__ Wtoh,
                                                    const short* __restrict__ Wtol,
                                                    const float* __restrict__ boff,
                                                    float* __restrict__ off) {
    __shared__ __align__(16) char smem[2 * 32 * AROW * 2 + 60 * SROW * 4]; // 46528 B
    short* Ah = (short*)smem;
    short* Al = Ah + 32 * AROW;
    float* Xs = (float*)(smem + 2 * 32 * AROW * 2);

    const int t    = threadIdx.x;
    const int lane = t & 63;
    const int wave = t >> 6;
    const int vb   = swizzle_blk(blockIdx.x);
    const int b    = vb / (TROW * TCOL);
    const int rem  = vb - b * (TROW * TCOL);
    const int i0   = (rem / TCOL) * 4;
    const int j0   = (rem % TCOL) * 8;
    const int spx  = t & 31;
    const int cg   = t >> 5;
    const int pr   = spx >> 3, pc = spx & 7;
    const int i    = i0 + pr, j = j0 + pc;
    const int l15  = lane & 15;
    const int quad = lane >> 4;
    const int mtb  = wave >> 1;
    const int ntb  = wave & 1;

    const float* xb = xT + (size_t)(b * HW) * 64;

    // hoisted boundary mask (chunk-invariant)
    int okm = 0;
#pragma unroll
    for (int n = 0; n < 9; ++n) {
        int ii = i + n / 3 - 1, jj = j + n % 3 - 1;
        okm |= (int)((ii >= 0) & (ii < H) & (jj >= 0) & (jj < W)) << n;
    }

    f32x4 acc = (f32x4){0.f, 0.f, 0.f, 0.f};

    for (int chunk = 0; chunk < 2; ++chunk) {
#pragma unroll
        for (int k = 0; k < 2; ++k) {
            int idx = k * 256 + t;
            if (idx < 480) {
                int slot = idx >> 3, e = idx & 7;
                int sr = slot / 10, sc = slot - sr * 10;
                int rr = i0 - 1 + sr, cc = j0 - 1 + sc;
                bool ok = (rr >= 0) & (rr < H) & (cc >= 0) & (cc < W);
                float4 v = make_float4(0.f, 0.f, 0.f, 0.f);
                if (ok) v = *(const float4*)(xb + (size_t)(rr * W + cc) * 64 + chunk * 32 + e * 4);
                *(float4*)&Xs[slot * SROW + e * 4] = v;
            }
        }
        __syncthreads();
        short* wrh = &Ah[spx * AROW + cg * 4];
        short* wrl = &Al[spx * AROW + cg * 4];
#pragma unroll
        for (int n = 0; n < 9; ++n) {
            int slot = (pr + n / 3) * 10 + (pc + n % 3);
            float4 v = make_float4(0.f, 0.f, 0.f, 0.f);
            if ((okm >> n) & 1) v = *(float4*)&Xs[slot * SROW + cg * 4];
            s16x4 h4, l4;
            split_bf4(v.x, v.y, v.z, v.w, h4, l4);
            *(s16x4*)(wrh + n * 32) = h4;
            *(s16x4*)(wrl + n * 32) = l4;
        }
        __syncthreads();
        const short* aph = &Ah[(mtb * 16 + l15) * AROW + quad * 8];
        const short* apl = &Al[(mtb * 16 + l15) * AROW + quad * 8];
        const short* bph = Wtoh + (ntb * 16 + l15) * K576 + chunk * KCHUNK + quad * 8;
        const short* bpl = Wtol + (ntb * 16 + l15) * K576 + chunk * KCHUNK + quad * 8;
#pragma unroll
        for (int kt = 0; kt < 9; ++kt) {
            bf16x8 afh = *(const bf16x8*)(aph + kt * 32);
            bf16x8 afl = *(const bf16x8*)(apl + kt * 32);
            bf16x8 bfh = *(const bf16x8*)(bph + kt * 32);
            bf16x8 bfl = *(const bf16x8*)(bpl + kt * 32);
            acc = __builtin_amdgcn_mfma_f32_16x16x32_bf16(afh, bfh, acc, 0, 0, 0);
            acc = __builtin_amdgcn_mfma_f32_16x16x32_bf16(afl, bfh, acc, 0, 0, 0);
            acc = __builtin_amdgcn_mfma_f32_16x16x32_bf16(afh, bfl, acc, 0, 0, 0);
        }
        __syncthreads();
    }

    float* Ld = (float*)smem;
    int n = ntb * 16 + l15;
    if (n < OFFS) {
        float bi = (n < NOFF) ? boff[n] : 0.0f;
        int pxr = mtb * 16 + quad * 4;
#pragma unroll
        for (int r = 0; r < 4; ++r)
            Ld[(pxr + r) * OFFS + n] = acc[r] + bi;
    }
    __syncthreads();
    {
        int px = t >> 3, c4 = t & 7;
        if (c4 < 5) {
            float4 v = *(float4*)&Ld[px * OFFS + c4 * 4];
            int ij = (i0 + (px >> 3)) * W + j0 + (px & 7);
            *(float4*)(off + (size_t)(b * HW + ij) * OFFS + c4 * 4) = v;
        }
    }
}

// ---------------------------------------------------------------------------
// Deformable sampling + conv as split-bf16 MFMA GEMM; 4x8 tile, 8x12x32ch
// border-replicated LDS patch + rare global fallback. Per-tap bilinear setup
// hoisted out of the chunk loop (regs). Epilogue fuses per-channel partial
// sum/sumsq (deterministic per-block writes into part).
// ---------------------------------------------------------------------------
template <bool OUT_NHWC>
__global__ __launch_bounds__(256, 3) void k_deform(const float* __restrict__ xT,
                                                   const float* __restrict__ off,
                                                   const short* __restrict__ Wtdh,
                                                   const short* __restrict__ Wtdl,
                                                   float* __restrict__ out,
                                                   float* __restrict__ part) {
    __shared__ __align__(16) char smem[2 * 32 * AROW * 2 + 96 * SROW * 4]; // 51712 B
    short* Ah = (short*)smem;
    short* Al = Ah + 32 * AROW;
    float* Xs = (float*)(smem + 2 * 32 * AROW * 2);

    const int t    = threadIdx.x;
    const int lane = t & 63;
    const int wave = t >> 6;
    const int vb   = swizzle_blk(blockIdx.x);
    const int b    = vb / (TROW * TCOL);
    const int rem  = vb - b * (TROW * TCOL);
    const int i0   = (rem / TCOL) * 4;
    const int j0   = (rem % TCOL) * 8;
    const int spx  = t & 31;
    const int cg   = t >> 5;
    const int pr   = spx >> 3, pc = spx & 7;
    const int i    = i0 + pr, j = j0 + pc;
    const int ij   = i * W + j;
    const int l15  = lane & 15;
    const int quad = lane >> 4;
    const int mtb  = wave >> 1;
    const int ntb0 = (wave & 1) * 2;

    const float* xb = xT + (size_t)(b * HW) * 64;

    float offa[20];
#pragma unroll
    for (int k = 0; k < 5; ++k)
        *(float4*)&offa[k * 4] = *(const float4*)(off + (size_t)(b * HW + ij) * OFFS + k * 4);

    // ---- hoisted per-tap bilinear setup (chunk-invariant) ----
    float g0a[9], g1a[9], g2a[9], g3a[9];
    int   slp[9];                 // packed patch slots, or -1 (fallback)
    int   cA[9], cB[9];           // packed global coords for fallback
#pragma unroll
    for (int n = 0; n < 9; ++n) {
        float px_f = (float)(i + n / 3) + offa[n];
        float py_f = (float)(j + n % 3) + offa[9 + n];
        float qx = floorf(px_f), qy = floorf(py_f);
        int ltx = min(max((int)qx, 0), H - 1);
        int lty = min(max((int)qy, 0), W - 1);
        int rbx = min(max((int)qx + 1, 0), H - 1);
        int rby = min(max((int)qy + 1, 0), W - 1);
        float px = fminf(fmaxf(px_f, 0.0f), (float)(H - 1));
        float py = fminf(fmaxf(py_f, 0.0f), (float)(W - 1));
        float alt = 1.0f + ((float)ltx - px);
        float arb = 1.0f - ((float)rbx - px);
        float blt = 1.0f + ((float)lty - py);
        float brb = 1.0f - ((float)rby - py);
        g0a[n] = alt * blt; g1a[n] = arb * brb;
        g2a[n] = alt * brb; g3a[n] = arb * blt;
        int slr = ltx - (i0 - 1), srr = rbx - (i0 - 1);
        int slc = lty - (j0 - 1), src = rby - (j0 - 1);
        bool inp = ((unsigned)slr < 8u) & ((unsigned)srr < 8u) &
                   ((unsigned)slc < 12u) & ((unsigned)src < 12u);
        slp[n] = inp ? ((slr * 12 + slc) | ((srr * 12 + src) << 8) |
                        ((slr * 12 + src) << 16) | ((srr * 12 + slc) << 24)) : -1;
        cA[n] = (ltx << 16) | lty;
        cB[n] = (rbx << 16) | rby;
    }

    f32x4 acc[2];
    acc[0] = (f32x4){0.f, 0.f, 0.f, 0.f};
    acc[1] = (f32x4){0.f, 0.f, 0.f, 0.f};

    for (int chunk = 0; chunk < 2; ++chunk) {
        const int ch = chunk * 32 + cg * 4;
#pragma unroll
        for (int k = 0; k < 3; ++k) {
            int idx = k * 256 + t;
            int slot = idx >> 3, e = idx & 7;
            int sr = slot / 12, sc = slot - sr * 12;
            int rr = min(max(i0 - 1 + sr, 0), H - 1);
            int cc = min(max(j0 - 1 + sc, 0), W - 1);
            float4 v = *(const float4*)(xb + (size_t)(rr * W + cc) * 64 + chunk * 32 + e * 4);
            *(float4*)&Xs[slot * SROW + e * 4] = v;
        }
        __syncthreads();
        short* wrh = &Ah[spx * AROW + cg * 4];
        short* wrl = &Al[spx * AROW + cg * 4];
#pragma unroll
        for (int n = 0; n < 9; ++n) {
            float4 v0, v1, v2, v3;
            int sp = slp[n];
            if (sp >= 0) {
                v0 = *(float4*)&Xs[(sp & 255) * SROW + cg * 4];
                v1 = *(float4*)&Xs[((sp >> 8) & 255) * SROW + cg * 4];
                v2 = *(float4*)&Xs[((sp >> 16) & 255) * SROW + cg * 4];
                v3 = *(float4*)&Xs[((sp >> 24) & 255) * SROW + cg * 4];
            } else {
                int ltx = cA[n] >> 16, lty = cA[n] & 0xffff;
                int rbx = cB[n] >> 16, rby = cB[n] & 0xffff;
                v0 = *(const float4*)(xb + (size_t)(ltx * W + lty) * 64 + ch);
                v1 = *(const float4*)(xb + (size_t)(rbx * W + rby) * 64 + ch);
                v2 = *(const float4*)(xb + (size_t)(ltx * W + rby) * 64 + ch);
                v3 = *(const float4*)(xb + (size_t)(rbx * W + lty) * 64 + ch);
            }
            float g0 = g0a[n], g1 = g1a[n], g2 = g2a[n], g3 = g3a[n];
            float s0 = g0 * v0.x + g1 * v1.x + g2 * v2.x + g3 * v3.x;
            float s1 = g0 * v0.y + g1 * v1.y + g2 * v2.y + g3 * v3.y;
            float s2 = g0 * v0.z + g1 * v1.z + g2 * v2.z + g3 * v3.z;
            float s3 = g0 * v0.w + g1 * v1.w + g2 * v2.w + g3 * v3.w;
            s16x4 h4, l4;
            split_bf4(s0, s1, s2, s3, h4, l4);
            *(s16x4*)(wrh + n * 32) = h4;
            *(s16x4*)(wrl + n * 32) = l4;
        }
        __syncthreads();
        const short* aph = &Ah[(mtb * 16 + l15) * AROW + quad * 8];
        const short* apl = &Al[(mtb * 16 + l15) * AROW + quad * 8];
        const short* bh0 = Wtdh + (ntb0 * 16 + l15) * K576 + chunk * KCHUNK + quad * 8;
        const short* bl0 = Wtdl + (ntb0 * 16 + l15) * K576 + chunk * KCHUNK + quad * 8;
#pragma unroll
        for (int kt = 0; kt < 9; ++kt) {
            bf16x8 afh = *(const bf16x8*)(aph + kt * 32);
            bf16x8 afl = *(const bf16x8*)(apl + kt * 32);
#pragma unroll
            for (int nt = 0; nt < 2; ++nt) {
                bf16x8 bfh = *(const bf16x8*)(bh0 + nt * 16 * K576 + kt * 32);
                bf16x8 bfl = *(const bf16x8*)(bl0 + nt * 16 * K576 + kt * 32);
                acc[nt] = __builtin_amdgcn_mfma_f32_16x16x32_bf16(afh, bfh, acc[nt], 0, 0, 0);
                acc[nt] = __builtin_amdgcn_mfma_f32_16x16x32_bf16(afl, bfh, acc[nt], 0, 0, 0);
                acc[nt] = __builtin_amdgcn_mfma_f32_16x16x32_bf16(afh, bfl, acc[nt], 0, 0, 0);
            }
        }
        __syncthreads();
    }

    float* Ld = (float*)smem;
    if (OUT_NHWC) {
        int pxr = mtb * 16 + quad * 4;
#pragma unroll
        for (int nt = 0; nt < 2; ++nt) {
            int c = (ntb0 + nt) * 16 + l15;
#pragma unroll
            for (int r = 0; r < 4; ++r)
                Ld[(pxr + r) * 72 + c] = acc[nt][r];
        }
        __syncthreads();
#pragma unroll
        for (int r = 0; r < 2; ++r) {
            int px = (t >> 4) + r * 16, c4 = t & 15;
            float4 v = *(float4*)&Ld[px * 72 + c4 * 4];
            int pij = (i0 + (px >> 3)) * W + j0 + (px & 7);
            *(float4*)(out + (size_t)(b * HW + pij) * 64 + c4 * 4) = v;
        }
    } else {
        int pxr = mtb * 16 + quad * 4;
#pragma unroll
        for (int nt = 0; nt < 2; ++nt) {
            int c = (ntb0 + nt) * 16 + l15;
#pragma unroll
            for (int r = 0; r < 4; ++r)
                Ld[c * 36 + pxr + r] = acc[nt][r];
        }
        __syncthreads();
#pragma unroll
        for (int cc = 0; cc < 2; ++cc) {
            int c = cc * 32 + (t >> 3), p4 = t & 7;
            float4 v = *(float4*)&Ld[c * 36 + p4 * 4];
            int px = p4 * 4;
            int pij = (i0 + (px >> 3)) * W + j0 + (px & 7);
            *(float4*)(out + (size_t)(b * COUT + c) * HW + pij) = v;
        }
    }

    // ---- fused per-channel partial stats (deterministic) ----
    {
        float* Sr = Xs;                 // patch area free now; disjoint from Ld
        int c = t & 63, g = t >> 6;
        float s = 0.f, q = 0.f;
#pragma unroll
        for (int k = 0; k < 8; ++k) {
            int px = g * 8 + k;
            float v = OUT_NHWC ? Ld[px * 72 + c] : Ld[c * 36 + px];
            s += v; q += v * v;
        }
        Sr[g * 64 + c]       = s;
        Sr[256 + g * 64 + c] = q;
        __syncthreads();
        if (t < 64) {
            float ts = Sr[t] + Sr[64 + t] + Sr[128 + t] + Sr[192 + t];
            float tq = Sr[256 + t] + Sr[320 + t] + Sr[384 + t] + Sr[448 + t];
            part[t * PSTRIDE + blockIdx.x]         = ts;
            part[PQOFF + t * PSTRIDE + blockIdx.x] = tq;
        }
    }
}

// ---------------------------------------------------------------------------
// Reduce per-block partials -> per-channel scale/shift. grid = 64 (1 ch/blk).
// ---------------------------------------------------------------------------
__global__ __launch_bounds__(256) void k_stats2(const float* __restrict__ part,
                                                const float* __restrict__ gamma,
                                                const float* __restrict__ beta,
                                                float* __restrict__ ss) {
    int c = blockIdx.x, t = threadIdx.x;
    float s = 0.f, q = 0.f;
    for (int k = t; k < NBLK; k += 256) {
        s += part[c * PSTRIDE + k];
        q += part[PQOFF + c * PSTRIDE + k];
    }
#pragma unroll
    for (int d = 32; d > 0; d >>= 1) {
        s += __shfl_down(s, d, 64);
        q += __shfl_down(q, d, 64);
    }
    __shared__ float red[8];
    int wv = t >> 6;
    if ((t & 63) == 0) { red[wv] = s; red[4 + wv] = q; }
    __syncthreads();
    if (t == 0) {
        float ts = red[0] + red[1] + red[2] + red[3];
        float tq = red[4] + red[5] + red[6] + red[7];
        const float inv_m = 1.0f / (float)(BATCH * HW);
        float mu    = ts * inv_m;
        float var   = tq * inv_m - mu * mu;
        float scale = rsqrtf(var + 1e-5f) * gamma[c];
        ss[c]      = scale;
        ss[64 + c] = beta[c] - mu * scale;
    }
}

// ---------------------------------------------------------------------------
// BN+ReLU on NHWC (stage 1).
// ---------------------------------------------------------------------------
__global__ __launch_bounds__(256) void k_bnrelu_nhwc(const float* __restrict__ y,
                                                     const float* __restrict__ ss,
                                                     float* __restrict__ out) {
    size_t idx = ((size_t)blockIdx.x * 256 + threadIdx.x) * 4;
    int c4 = (int)(idx & 63);
    float4 sc = *(const float4*)(ss + c4);
    float4 sh = *(const float4*)(ss + 64 + c4);
    float4 v  = *(const float4*)(y + idx);
    float4 r;
    r.x = fmaxf(fmaf(v.x, sc.x, sh.x), 0.f);
    r.y = fmaxf(fmaf(v.y, sc.y, sh.y), 0.f);
    r.z = fmaxf(fmaf(v.z, sc.z, sh.z), 0.f);
    r.w = fmaxf(fmaf(v.w, sc.w, sh.w), 0.f);
    *(float4*)(out + idx) = r;
}

// ---------------------------------------------------------------------------
// BN+ReLU on NCHW, IN-PLACE (stage 2).
// ---------------------------------------------------------------------------
__global__ __launch_bounds__(256) void k_bnrelu_nchw(float* __restrict__ y,
                                                     const float* __restrict__ ss) {
    int c = (blockIdx.x / 49) % COUT;
    float scale = ss[c], shift = ss[64 + c];
    size_t idx = ((size_t)blockIdx.x * 1024) + threadIdx.x * 4;
    float4 v = *(const float4*)(y + idx);
    float4 r;
    r.x = fmaxf(fmaf(v.x, scale, shift), 0.f);
    r.y = fmaxf(fmaf(v.y, scale, shift), 0.f);
    r.z = fmaxf(fmaf(v.z, scale, shift), 0.f);
    r.w = fmaxf(fmaf(v.w, scale, shift), 0.f);
    *(float4*)(y + idx) = r;
}

// ---------------------------------------------------------------------------
// Workspace (~36 MB): weights 216 KB | part 2 MB | ss 512 B |
// bufC(off20) 8.0 MB | bufB(xT / y1 NHWC) 25.7 MB.
// ---------------------------------------------------------------------------
extern "C" void kernel_launch(void* const* d_in, const int* in_sizes, int n_in,
                              void* d_out, int out_size, void* d_ws, size_t ws_size,
                              hipStream_t stream) {
    const float* x       = (const float*)d_in[0];
    const float* w_off1  = (const float*)d_in[1];
    const float* b_off1  = (const float*)d_in[2];
    const float* w_conv1 = (const float*)d_in[3];
    const float* gamma1  = (const float*)d_in[4];
    const float* beta1   = (const float*)d_in[5];
    const float* w_off2  = (const float*)d_in[6];
    const float* b_off2  = (const float*)d_in[7];
    const float* w_conv2 = (const float*)d_in[8];
    const float* gamma2  = (const float*)d_in[9];
    const float* beta2   = (const float*)d_in[10];
    float* out = (float*)d_out;

    char*  wsb  = (char*)d_ws;
    short* Wtdh = (short*)wsb;                           // 73728
    short* Wtdl = (short*)(wsb + 73728);                 // 73728
    short* Wtoh = (short*)(wsb + 147456);                // 36864
    short* Wtol = (short*)(wsb + 184320);                // 36864
    float* part = (float*)(wsb + 221184);                // 2 MB (2*64*4096*4)
    float* ss   = (float*)(wsb + 2318336);               // 512
    float* bufC = (float*)(wsb + 2318848);               // off20: 8028160
    float* bufB = (float*)(wsb + 10347008);              // xT/y1: 25690112

    const int tp_blocks = (BATCH * HW) / 64;             // 1568
    const int bn_blocks = (BATCH * COUT * HW) / 1024;    // 6272

    // ---- stage 1 ----
    k_prepw      <<<216, 256, 0, stream>>>(w_conv1, w_off1, Wtdh, Wtdl, Wtoh, Wtol);
    k_transpose  <<<tp_blocks, 256, 0, stream>>>(x, bufB);
    k_offconv    <<<NBLK, 256, 0, stream>>>(bufB, Wtoh, Wtol, b_off1, bufC);
    k_deform<true><<<NBLK, 256, 0, stream>>>(bufB, bufC, Wtdh, Wtdl, out, part);
    k_stats2     <<<64, 256, 0, stream>>>(part, gamma1, beta1, ss);
    k_bnrelu_nhwc<<<bn_blocks, 256, 0, stream>>>(out, ss, bufB);   // y1 (NHWC)

    // ---- stage 2 ----
    k_prepw      <<<216, 256, 0, stream>>>(w_conv2, w_off2, Wtdh, Wtdl, Wtoh, Wtol);
    k_offconv    <<<NBLK, 256, 0, stream>>>(bufB, Wtoh, Wtol, b_off2, bufC);
    k_deform<false><<<NBLK, 256, 0, stream>>>(bufB, bufC, Wtdh, Wtdl, out, part);
    k_stats2     <<<64, 256, 0, stream>>>(part, gamma2, beta2, ss);
    k_bnrelu_nchw<<<bn_blocks, 256, 0, stream>>>(out, ss);         // in-place
}